// Round 13
// baseline (314.083 us; speedup 1.0000x reference)
//
#include <hip/hip_runtime.h>
#include <hip/hip_bf16.h>
#include <math.h>

#define N_NODES 1024
#define NE      4096
#define HDIM    256
// SCALE * log2(e) folded into Q: scores come out in log2 units
#define QSCALE  0.2550348634f

typedef __hip_bfloat16 bf16;
typedef __attribute__((ext_vector_type(8))) short bf16x8;
typedef __attribute__((ext_vector_type(4))) float f32x4;

__device__ __forceinline__ float u2f(unsigned short u) {
  return __uint_as_float(((unsigned)u) << 16);
}
__device__ __forceinline__ short f2bs(float x) {  // fp32 -> bf16 bits, RNE
  unsigned u = __float_as_uint(x);
  unsigned r = u + 0x7FFFu + ((u >> 16) & 1u);
  return (short)(r >> 16);
}
__device__ __forceinline__ float gelu_f(float x) {
  return 0.5f * x * (1.0f + erff(x * 0.70710678118654752f));
}
__device__ __forceinline__ short rdbf(const void* p, int i, int flag) {
  return flag ? ((const short*)p)[i] : f2bs(((const float*)p)[i]);
}
__device__ __forceinline__ float fexp2(float x) {
#if __has_builtin(__builtin_amdgcn_exp2f)
  return __builtin_amdgcn_exp2f(x);
#else
  return exp2f(x);
#endif
}
// pack two fp32 into (hi<<16)|(lo) bf16 pair, truncating (v4-validated)
__device__ __forceinline__ unsigned pk2(float lo, float hi) {
  return (__float_as_uint(hi) & 0xFFFF0000u) | (__float_as_uint(lo) >> 16);
}
// RNE pack of two fp32 into bf16 pair
__device__ __forceinline__ unsigned pk2r(float lo, float hi) {
  return (unsigned)(unsigned short)f2bs(lo) |
         ((unsigned)(unsigned short)f2bs(hi) << 16);
}

// ---------- dtype probe + cnt zero ----------
__global__ __launch_bounds__(64) void k_detect(const unsigned* __restrict__ w,
                                               int* __restrict__ flag,
                                               int* __restrict__ cnt) {
  int t = threadIdx.x;
  int c = 0;
  for (int i = 0; i < 16; ++i) {
    unsigned v = w[t * 16 + i];
    unsigned e = (v >> 7) & 0xFFu;
    c += (e >= 100u && e <= 132u) ? 1 : 0;
  }
#pragma unroll
  for (int k = 1; k < 64; k <<= 1) c += __shfl_xor(c, k, 64);
  if (t == 0) *flag = (c > 512) ? 1 : 0;  // 1 = bf16, 0 = fp32
#pragma unroll
  for (int j = 0; j < 16; ++j) cnt[t * 16 + j] = 0;
}

// ---------- merged prologue: weights + small params + inverse edges ----------
struct WPtrs { const void* w_emb; const void* w_h; const void* in_w;
               const void* out_w; const void* up_w; };
struct PPtrs { const void* p[9]; };
__global__ __launch_bounds__(256) void k_prep(WPtrs a, PPtrs pp,
                                              const int* __restrict__ tgt,
                                              short* __restrict__ Wt,
                                              float* __restrict__ prm,
                                              int* __restrict__ cnt,
                                              int* __restrict__ inv,
                                              const int* __restrict__ flag) {
  int i = blockIdx.x * 256 + threadIdx.x;
  const int fl = *flag;
  if (i < 1064960) {
    if (i < 16384) {                       // W_emb [64][256]
      int k = i >> 8, n = i & 255;
      Wt[n * 64 + k] = rdbf(a.w_emb, i, fl);
    } else if (i < 81920) {                // W_h [256][256]
      int j = i - 16384;
      int k = j >> 8, n = j & 255;
      Wt[16384 + n * 256 + k] = rdbf(a.w_h, j, fl);
    } else if (i < 671744) {               // in_w [3][256][768]
      int j = i - 81920;
      int t = j / 196608, jj = j % 196608;
      int k = jj / 768, n = jj % 768;
      Wt[81920 + t * 196608 + n * 256 + k] = rdbf(a.in_w, j, fl);
    } else if (i < 868352) {               // out_w [3][256][256]
      int j = i - 671744;
      int t = j >> 16, jj = j & 65535;
      int k = jj >> 8, n = jj & 255;
      Wt[671744 + t * 65536 + n * 256 + k] = rdbf(a.out_w, j, fl);
    } else {                               // up_w [3][256][256]
      int j = i - 868352;
      int t = j >> 16, jj = j & 65535;
      int k = jj >> 8, n = jj & 255;
      Wt[868352 + t * 65536 + n * 256 + k] = rdbf(a.up_w, j, fl);
    }
  } else if (i < 1072384) {                // small params -> fp32
    int j = i - 1064960;
    const int sz[9] = {256, 256, 768, 768, 2304, 768, 768, 768, 768};
    int seg = 0, off = j;
    while (off >= sz[seg]) { off -= sz[seg]; ++seg; }
    prm[j] = fl ? u2f(((const unsigned short*)pp.p[seg])[off])
                : ((const float*)pp.p[seg])[off];
  } else if (i < 1076480) {                // inverse edge list
    int e = i - 1072384;
    int t = tgt[e];
    int s = atomicAdd(&cnt[t], 1);
    if (s < 8) inv[t * 8 + s] = e;
  }
}

// ---------- MFMA GEMM: full-K LDS, ONE barrier, XOR-swizzled ----------
// C = epi(A[MxK]bf16 @ Wt[NxK]bf16^T + bias). RAW=true: A is the raw bond
// input (probed dtype) -- fuses the bond conversion.
template <int K, bool RAW, bool GELU, bool WF, bool WB>
__global__ __launch_bounds__(256) void k_mgemm(const short* __restrict__ A,
                                               const short* __restrict__ Bt,
                                               const float* __restrict__ bias,
                                               float* __restrict__ outF,
                                               short* __restrict__ outB,
                                               const int* __restrict__ flag,
                                               int M, int N) {
  __shared__ alignas(16) short As[64 * K];
  __shared__ alignas(16) short Bs[64 * K];
  const int tid = threadIdx.x;
  const int wave = tid >> 6, lane = tid & 63;
  const int m = lane & 15, quad = lane >> 4;
  const int bm = blockIdx.x * 64, bn = blockIdx.y * 64;
  const int m0 = (wave & 1) * 32, n0 = (wave >> 1) * 32;

  constexpr int CPR = K >> 3;
  constexpr int CPT = K >> 5;

  const int fl = RAW ? *flag : 1;

  int4 ra[CPT], rb[CPT];
#pragma unroll
  for (int i = 0; i < CPT; ++i) {
    const int c = tid + (i << 8);
    const int row = c / CPR, kc = c % CPR;
    if (RAW && !fl) {
      const float* af = (const float*)A + (size_t)(bm + row) * K + kc * 8;
      unsigned* vu = (unsigned*)&ra[i];
      vu[0] = pk2r(af[0], af[1]);
      vu[1] = pk2r(af[2], af[3]);
      vu[2] = pk2r(af[4], af[5]);
      vu[3] = pk2r(af[6], af[7]);
    } else {
      ra[i] = *(const int4*)(A + (size_t)(bm + row) * K + kc * 8);
    }
    rb[i] = *(const int4*)(Bt + (size_t)(bn + row) * K + kc * 8);
  }
#pragma unroll
  for (int i = 0; i < CPT; ++i) {
    const int c = tid + (i << 8);
    const int row = c / CPR, kc = c % CPR;
    *(int4*)&As[row * K + ((kc ^ (row & 7)) << 3)] = ra[i];
    *(int4*)&Bs[row * K + ((kc ^ (row & 7)) << 3)] = rb[i];
  }
  __syncthreads();

  f32x4 acc[2][2];
  acc[0][0] = acc[0][1] = acc[1][0] = acc[1][1] = (f32x4){0.f, 0.f, 0.f, 0.f};

  const int sw = m & 7;
#pragma unroll
  for (int ks = 0; ks < K / 32; ++ks) {
    const int ca = ((ks * 4 + quad) ^ sw) << 3;
    bf16x8 a0 = *(const bf16x8*)&As[(m0 + m) * K + ca];
    bf16x8 a1 = *(const bf16x8*)&As[(m0 + 16 + m) * K + ca];
    bf16x8 b0 = *(const bf16x8*)&Bs[(n0 + m) * K + ca];
    bf16x8 b1 = *(const bf16x8*)&Bs[(n0 + 16 + m) * K + ca];
    acc[0][0] = __builtin_amdgcn_mfma_f32_16x16x32_bf16(a0, b0, acc[0][0], 0, 0, 0);
    acc[0][1] = __builtin_amdgcn_mfma_f32_16x16x32_bf16(a0, b1, acc[0][1], 0, 0, 0);
    acc[1][0] = __builtin_amdgcn_mfma_f32_16x16x32_bf16(a1, b0, acc[1][0], 0, 0, 0);
    acc[1][1] = __builtin_amdgcn_mfma_f32_16x16x32_bf16(a1, b1, acc[1][1], 0, 0, 0);
  }

#pragma unroll
  for (int i = 0; i < 2; ++i)
#pragma unroll
    for (int j = 0; j < 2; ++j) {
      const int col = bn + n0 + j * 16 + m;
      const float bv = bias[col];
#pragma unroll
      for (int r = 0; r < 4; ++r) {
        const int row = bm + m0 + i * 16 + quad * 4 + r;
        float v = acc[i][j][r] + bv;
        if (GELU) v = gelu_f(v);
        if (WF) outF[(size_t)row * N + col] = v;
        if (WB) outB[(size_t)row * N + col] = f2bs(v);
      }
    }
}

// out-projection GEMM with FUSED split-merge (deletes k_merge):
// t_ij = (merge(Opart,lpart)) @ Wt_out^T + bias + 2*r, written bf16.
__global__ __launch_bounds__(256) void k_mgemm_out(const short* __restrict__ Opart,
                                                   const float* __restrict__ lpart,
                                                   const short* __restrict__ Bt,
                                                   const float* __restrict__ bias,
                                                   const float* __restrict__ res,
                                                   short* __restrict__ outB) {
  constexpr int K = 256;
  __shared__ alignas(16) short As[64 * K];
  __shared__ alignas(16) short Bs[64 * K];
  const int tid = threadIdx.x;
  const int wave = tid >> 6, lane = tid & 63;
  const int m = lane & 15, quad = lane >> 4;
  const int bm = blockIdx.x * 64, bn = blockIdx.y * 64;
  const int m0 = (wave & 1) * 32, n0 = (wave >> 1) * 32;

  int4 ra[8], rb[8];
#pragma unroll
  for (int i = 0; i < 8; ++i) {
    const int c = tid + (i << 8);
    const int row = c >> 5, kc = c & 31;
    const int R = bm + row, head = kc >> 2;
    float o[8] = {0.f, 0.f, 0.f, 0.f, 0.f, 0.f, 0.f, 0.f};
    float l = 0.f;
#pragma unroll
    for (int s = 0; s < 4; ++s) {
      int4 ov = *(const int4*)(Opart + (size_t)s * 1048576 + (size_t)R * 256 + kc * 8);
      const unsigned short* os = (const unsigned short*)&ov;
#pragma unroll
      for (int j = 0; j < 8; ++j) o[j] += u2f(os[j]);
      l += lpart[(size_t)(s * 8 + head) * 4096 + R];
    }
    const float inv = 1.0f / l;
    unsigned* vu = (unsigned*)&ra[i];
    vu[0] = pk2r(o[0] * inv, o[1] * inv);
    vu[1] = pk2r(o[2] * inv, o[3] * inv);
    vu[2] = pk2r(o[4] * inv, o[5] * inv);
    vu[3] = pk2r(o[6] * inv, o[7] * inv);
    rb[i] = *(const int4*)(Bt + (size_t)(bn + row) * K + kc * 8);
  }
#pragma unroll
  for (int i = 0; i < 8; ++i) {
    const int c = tid + (i << 8);
    const int row = c >> 5, kc = c & 31;
    *(int4*)&As[row * K + ((kc ^ (row & 7)) << 3)] = ra[i];
    *(int4*)&Bs[row * K + ((kc ^ (row & 7)) << 3)] = rb[i];
  }
  __syncthreads();

  f32x4 acc[2][2];
  acc[0][0] = acc[0][1] = acc[1][0] = acc[1][1] = (f32x4){0.f, 0.f, 0.f, 0.f};

  const int sw = m & 7;
#pragma unroll
  for (int ks = 0; ks < K / 32; ++ks) {
    const int ca = ((ks * 4 + quad) ^ sw) << 3;
    bf16x8 a0 = *(const bf16x8*)&As[(m0 + m) * K + ca];
    bf16x8 a1 = *(const bf16x8*)&As[(m0 + 16 + m) * K + ca];
    bf16x8 b0 = *(const bf16x8*)&Bs[(n0 + m) * K + ca];
    bf16x8 b1 = *(const bf16x8*)&Bs[(n0 + 16 + m) * K + ca];
    acc[0][0] = __builtin_amdgcn_mfma_f32_16x16x32_bf16(a0, b0, acc[0][0], 0, 0, 0);
    acc[0][1] = __builtin_amdgcn_mfma_f32_16x16x32_bf16(a0, b1, acc[0][1], 0, 0, 0);
    acc[1][0] = __builtin_amdgcn_mfma_f32_16x16x32_bf16(a1, b0, acc[1][0], 0, 0, 0);
    acc[1][1] = __builtin_amdgcn_mfma_f32_16x16x32_bf16(a1, b1, acc[1][1], 0, 0, 0);
  }

#pragma unroll
  for (int i = 0; i < 2; ++i)
#pragma unroll
    for (int j = 0; j < 2; ++j) {
      const int col = bn + n0 + j * 16 + m;
      const float bv = bias[col];
#pragma unroll
      for (int r = 0; r < 4; ++r) {
        const int row = bm + m0 + i * 16 + quad * 4 + r;
        float v = acc[i][j][r] + bv + 2.0f * res[(size_t)row * 256 + col];
        outB[(size_t)row * 256 + col] = f2bs(v);
      }
    }
}

// up GEMM with FUSED LayerNorm+GELU (deletes k_ln_gelu): grid 256 x 16 rows,
// full 256-col output per block via 4 N-quadrant loop -> row-LN block-local.
// h = gelu(LN(t_ij @ Wt_up^T + up_b)*g + b); final layer also writes d_out.
__global__ __launch_bounds__(256) void k_up_ln(const short* __restrict__ A,
                                               const short* __restrict__ Bt,
                                               const float* __restrict__ bias,
                                               const float* __restrict__ g,
                                               const float* __restrict__ b,
                                               float* __restrict__ hout,
                                               void* __restrict__ finalout,
                                               const int* __restrict__ flag) {
  constexpr int K = 256;
  __shared__ alignas(16) short As[16 * K];
  __shared__ alignas(16) short Bs[64 * K];
  __shared__ float red1[4][16], red2[4][16];
  const int tid = threadIdx.x;
  const int wave = tid >> 6, lane = tid & 63;
  const int m = lane & 15, quad = lane >> 4;
  const int bm = blockIdx.x * 16;

  // stage A (16 rows x 256) once
  int4 qa[2];
#pragma unroll
  for (int i = 0; i < 2; ++i) {
    const int c = tid + (i << 8);
    const int row = c >> 5, kc = c & 31;
    qa[i] = *(const int4*)(A + (size_t)(bm + row) * K + kc * 8);
  }
#pragma unroll
  for (int i = 0; i < 2; ++i) {
    const int c = tid + (i << 8);
    const int row = c >> 5, kc = c & 31;
    *(int4*)&As[row * K + ((kc ^ (row & 7)) << 3)] = qa[i];
  }

  int4 rb[8];
#pragma unroll
  for (int i = 0; i < 8; ++i) {
    const int c = tid + (i << 8);
    const int row = c >> 5, kc = c & 31;
    rb[i] = *(const int4*)(Bt + (size_t)row * K + kc * 8);
  }

  f32x4 acc[4];
  acc[0] = acc[1] = acc[2] = acc[3] = (f32x4){0.f, 0.f, 0.f, 0.f};
  const int sw = m & 7;

#pragma unroll 1
  for (int bn = 0; bn < 4; ++bn) {
    if (bn) __syncthreads();
#pragma unroll
    for (int i = 0; i < 8; ++i) {
      const int c = tid + (i << 8);
      const int row = c >> 5, kc = c & 31;
      *(int4*)&Bs[row * K + ((kc ^ (row & 7)) << 3)] = rb[i];
    }
    __syncthreads();
    if (bn < 3) {
#pragma unroll
      for (int i = 0; i < 8; ++i) {
        const int c = tid + (i << 8);
        const int row = c >> 5, kc = c & 31;
        rb[i] = *(const int4*)(Bt + (size_t)((bn + 1) * 64 + row) * K + kc * 8);
      }
    }
#pragma unroll
    for (int ks = 0; ks < 8; ++ks) {
      const int ca = ((ks * 4 + quad) ^ sw) << 3;
      bf16x8 af = *(const bf16x8*)&As[m * K + ca];
      bf16x8 bf = *(const bf16x8*)&Bs[(wave * 16 + m) * K + ca];
      acc[bn] = __builtin_amdgcn_mfma_f32_16x16x32_bf16(af, bf, acc[bn], 0, 0, 0);
    }
  }

  // epilogue: u = acc + bias; row-LN over 256 cols; gelu; store
  float u[4][4];
#pragma unroll
  for (int bn = 0; bn < 4; ++bn) {
    const float bv = bias[bn * 64 + wave * 16 + m];
#pragma unroll
    for (int r = 0; r < 4; ++r) u[bn][r] = acc[bn][r] + bv;
  }
  float s[4];
#pragma unroll
  for (int r = 0; r < 4; ++r)
    s[r] = (u[0][r] + u[1][r]) + (u[2][r] + u[3][r]);
#pragma unroll
  for (int k = 1; k < 16; k <<= 1)
#pragma unroll
    for (int r = 0; r < 4; ++r) s[r] += __shfl_xor(s[r], k, 64);
  if (m == 0)
#pragma unroll
    for (int r = 0; r < 4; ++r) red1[wave][quad * 4 + r] = s[r];
  __syncthreads();
  float mean[4];
#pragma unroll
  for (int r = 0; r < 4; ++r) {
    const int rr = quad * 4 + r;
    mean[r] = (red1[0][rr] + red1[1][rr] + red1[2][rr] + red1[3][rr]) *
              (1.0f / HDIM);
  }
  float sq[4];
#pragma unroll
  for (int r = 0; r < 4; ++r) {
    float a0 = u[0][r] - mean[r], a1 = u[1][r] - mean[r];
    float a2 = u[2][r] - mean[r], a3 = u[3][r] - mean[r];
    sq[r] = (a0 * a0 + a1 * a1) + (a2 * a2 + a3 * a3);
  }
#pragma unroll
  for (int k = 1; k < 16; k <<= 1)
#pragma unroll
    for (int r = 0; r < 4; ++r) sq[r] += __shfl_xor(sq[r], k, 64);
  if (m == 0)
#pragma unroll
    for (int r = 0; r < 4; ++r) red2[wave][quad * 4 + r] = sq[r];
  __syncthreads();
  const int fl = finalout ? *flag : 0;
#pragma unroll
  for (int r = 0; r < 4; ++r) {
    const int rr = quad * 4 + r;
    const float var = (red2[0][rr] + red2[1][rr] + red2[2][rr] + red2[3][rr]) *
                      (1.0f / HDIM);
    const float rs = rsqrtf(var + 1e-5f);
    const int row = bm + rr;
#pragma unroll
    for (int bn = 0; bn < 4; ++bn) {
      const int col = bn * 64 + wave * 16 + m;
      const float xh = (u[bn][r] - mean[r]) * rs * g[col] + b[col];
      const float out = gelu_f(xh);
      hout[(size_t)row * HDIM + col] = out;
      if (finalout) {
        if (fl)
          ((bf16*)finalout)[(size_t)row * HDIM + col] = __float2bfloat16(out);
        else
          ((float*)finalout)[(size_t)row * HDIM + col] = out;
      }
    }
  }
}

// qkv variant (K=256, full-K single-barrier staging): writes
// Qh/Kh[head][4096][32] (Q pre-scaled, K linear), Vt[head][32][4096] with
// the in-tile key PERMUTATION baked in:
//   key T -> (T&~63) + ((T>>5)&1)*32 + ((T>>2)&3)*8 + ((T>>4)&1)*4 + (T&3)
// so flash's PV A-fragment needs no LDS round-trip.
__global__ __launch_bounds__(256) void k_mgemm_qkv(const short* __restrict__ A,
                                                   const short* __restrict__ Bt,
                                                   const float* __restrict__ bias,
                                                   short* __restrict__ Qh,
                                                   short* __restrict__ Kh,
                                                   short* __restrict__ Vt) {
  constexpr int K = 256;
  __shared__ alignas(16) short As[64 * K];
  __shared__ alignas(16) short Bs[64 * K];
  const int tid = threadIdx.x;
  const int wave = tid >> 6, lane = tid & 63;
  const int m = lane & 15, quad = lane >> 4;
  const int bm = blockIdx.x * 64, bn = blockIdx.y * 64;
  const int m0 = (wave & 1) * 32, n0 = (wave >> 1) * 32;

  int4 ra[8], rb[8];
#pragma unroll
  for (int i = 0; i < 8; ++i) {
    const int c = tid + (i << 8);
    const int row = c >> 5, kc = c & 31;
    ra[i] = *(const int4*)(A + (size_t)(bm + row) * K + kc * 8);
    rb[i] = *(const int4*)(Bt + (size_t)(bn + row) * K + kc * 8);
  }
#pragma unroll
  for (int i = 0; i < 8; ++i) {
    const int c = tid + (i << 8);
    const int row = c >> 5, kc = c & 31;
    *(int4*)&As[row * K + ((kc ^ (row & 7)) << 3)] = ra[i];
    *(int4*)&Bs[row * K + ((kc ^ (row & 7)) << 3)] = rb[i];
  }
  __syncthreads();

  f32x4 acc[2][2];
  acc[0][0] = acc[0][1] = acc[1][0] = acc[1][1] = (f32x4){0.f, 0.f, 0.f, 0.f};

  const int sw = m & 7;
#pragma unroll
  for (int ks = 0; ks < K / 32; ++ks) {
    const int ca = ((ks * 4 + quad) ^ sw) << 3;
    bf16x8 a0 = *(const bf16x8*)&As[(m0 + m) * K + ca];
    bf16x8 a1 = *(const bf16x8*)&As[(m0 + 16 + m) * K + ca];
    bf16x8 b0 = *(const bf16x8*)&Bs[(n0 + m) * K + ca];
    bf16x8 b1 = *(const bf16x8*)&Bs[(n0 + 16 + m) * K + ca];
    acc[0][0] = __builtin_amdgcn_mfma_f32_16x16x32_bf16(a0, b0, acc[0][0], 0, 0, 0);
    acc[0][1] = __builtin_amdgcn_mfma_f32_16x16x32_bf16(a0, b1, acc[0][1], 0, 0, 0);
    acc[1][0] = __builtin_amdgcn_mfma_f32_16x16x32_bf16(a1, b0, acc[1][0], 0, 0, 0);
    acc[1][1] = __builtin_amdgcn_mfma_f32_16x16x32_bf16(a1, b1, acc[1][1], 0, 0, 0);
  }

#pragma unroll
  for (int i = 0; i < 2; ++i)
#pragma unroll
    for (int j = 0; j < 2; ++j) {
      const int col = bn + n0 + j * 16 + m;
      const float bv = bias[col];
      const int row0 = bm + m0 + i * 16 + quad * 4;
      if (col < 256) {
        const int head = col >> 5, d = col & 31;
#pragma unroll
        for (int r = 0; r < 4; ++r)
          Qh[(size_t)head * 131072 + (row0 + r) * 32 + d] =
              f2bs((acc[i][j][r] + bv) * QSCALE);
      } else if (col < 512) {
        const int c = col - 256, head = c >> 5, d = c & 31;
#pragma unroll
        for (int r = 0; r < 4; ++r)
          Kh[(size_t)head * 131072 + (row0 + r) * 32 + d] = f2bs(acc[i][j][r] + bv);
      } else {
        const int c = col - 512, head = c >> 5, d = c & 31;
        const int p0 = (row0 & ~63) + ((row0 >> 5) & 1) * 32 +
                       ((row0 >> 2) & 3) * 8 + ((row0 >> 4) & 1) * 4;
        ushort4 w;
        w.x = (unsigned short)f2bs(acc[i][j][0] + bv);
        w.y = (unsigned short)f2bs(acc[i][j][1] + bv);
        w.z = (unsigned short)f2bs(acc[i][j][2] + bv);
        w.w = (unsigned short)f2bs(acc[i][j][3] + bv);
        *(ushort4*)(Vt + (size_t)head * 131072 + d * 4096 + p0) = w;
      }
    }
}

// ---------- fused gather-aggregation + LN ----------
__global__ __launch_bounds__(256) void k_rln2(const int* __restrict__ tgt,
                                              const int* __restrict__ cnt,
                                              const int* __restrict__ inv,
                                              const float* __restrict__ h,
                                              const float* __restrict__ g,
                                              const float* __restrict__ b,
                                              float* __restrict__ r,
                                              short* __restrict__ xnb) {
  __shared__ float red1[4], red2[4];
  const int e = blockIdx.x, d = threadIdx.x;
  const int t = tgt[e];
  const int c = cnt[t];
  float S = 0.f;
  for (int j = 0; j < c; ++j)
    S += h[(size_t)inv[t * 8 + j] * HDIM + d];
  float rv = S - (float)c * h[(size_t)e * HDIM + d];
  r[(size_t)e * HDIM + d] = rv;

  float s = rv;
#pragma unroll
  for (int k = 1; k < 64; k <<= 1) s += __shfl_xor(s, k, 64);
  if ((d & 63) == 0) red1[d >> 6] = s;
  __syncthreads();
  float mean = (red1[0] + red1[1] + red1[2] + red1[3]) * (1.0f / HDIM);
  float diff = rv - mean;
  float sq = diff * diff;
#pragma unroll
  for (int k = 1; k < 64; k <<= 1) sq += __shfl_xor(sq, k, 64);
  if ((d & 63) == 0) red2[d >> 6] = sq;
  __syncthreads();
  float var = (red2[0] + red2[1] + red2[2] + red2[3]) * (1.0f / HDIM);
  xnb[(size_t)e * HDIM + d] = f2bs(diff * rsqrtf(var + 1e-5f) * g[d] + b[d]);
}

// ---------- MFMA flash attention v13: LDS-shared K/V, 64 q/wave ----------
__global__ __launch_bounds__(256) void k_flash4(const short* __restrict__ Qh,
                                                const short* __restrict__ Kh,
                                                const short* __restrict__ Vt,
                                                short* __restrict__ Opart,
                                                float* __restrict__ lpart) {
  __shared__ alignas(16) short Ks[64 * 40];
  __shared__ alignas(16) short Vs[32 * 70 + 8];
  const int head = blockIdx.y, split = blockIdx.z;
  const int tid = threadIdx.x;
  const int wave = tid >> 6, lane = tid & 63;
  const int m = lane & 15, quad = lane >> 4;
  const int q0 = blockIdx.x * 256 + wave * 64;

  const short* Qb = Qh + (size_t)head * 131072;
  const short* Kb = Kh + (size_t)head * 131072;
  const short* Vb = Vt + (size_t)head * 131072;

  bf16x8 qf[4];
#pragma unroll
  for (int a = 0; a < 4; ++a)
    qf[a] = *(const bf16x8*)(Qb + (q0 + a * 16 + m) * 32 + quad * 8);

  f32x4 O[4][2];
  f32x4 lacc[4];
#pragma unroll
  for (int a = 0; a < 4; ++a) {
    O[a][0] = O[a][1] = (f32x4){0.f, 0.f, 0.f, 0.f};
    lacc[a] = (f32x4){0.f, 0.f, 0.f, 0.f};
  }

  bf16x8 ones;
#pragma unroll
  for (int i = 0; i < 8; ++i) ones[i] = (short)0x3F80;  // bf16 1.0

  const int base = split * 1024;
  const int krow = tid >> 2, ko = (tid & 3) * 8;
  const int vrow = tid >> 3, vo = (tid & 7) * 8;
  const short* kstage = Kb + (size_t)(base + krow) * 32 + ko;   // + kb*2048
  const short* vstage = Vb + (size_t)vrow * 4096 + base + vo;   // + kb*64

  int4 rk = *(const int4*)(kstage);
  int4 rv = *(const int4*)(vstage);

#pragma unroll 1
  for (int kb = 0; kb < 16; ++kb) {
    __syncthreads();
    *(int4*)&Ks[krow * 40 + ko] = rk;
    *(int4*)&Vs[vrow * 70 + vo] = rv;
    __syncthreads();
    if (kb < 15) {
      rk = *(const int4*)(kstage + (kb + 1) * 2048);
      rv = *(const int4*)(vstage + (kb + 1) * 64);
    }

    bf16x8 kc0 = *(const bf16x8*)&Ks[(0 * 16 + m) * 40 + quad * 8];
    bf16x8 kc1 = *(const bf16x8*)&Ks[(1 * 16 + m) * 40 + quad * 8];
    bf16x8 kc2 = *(const bf16x8*)&Ks[(2 * 16 + m) * 40 + quad * 8];
    bf16x8 kc3 = *(const bf16x8*)&Ks[(3 * 16 + m) * 40 + quad * 8];
    bf16x8 vc0 = *(const bf16x8*)&Vs[m * 70 + quad * 8];
    bf16x8 vc1 = *(const bf16x8*)&Vs[(m + 16) * 70 + quad * 8];
    bf16x8 vc2 = *(const bf16x8*)&Vs[m * 70 + 32 + quad * 8];
    bf16x8 vc3 = *(const bf16x8*)&Vs[(m + 16) * 70 + 32 + quad * 8];

    const f32x4 z = {0.f, 0.f, 0.f, 0.f};
#pragma unroll
    for (int a = 0; a < 4; ++a) {
      f32x4 S0 = __builtin_amdgcn_mfma_f32_16x16x32_bf16(kc0, qf[a], z, 0, 0, 0);
      f32x4 S1 = __builtin_amdgcn_mfma_f32_16x16x32_bf16(kc1, qf[a], z, 0, 0, 0);
      f32x4 S2 = __builtin_amdgcn_mfma_f32_16x16x32_bf16(kc2, qf[a], z, 0, 0, 0);
      f32x4 S3 = __builtin_amdgcn_mfma_f32_16x16x32_bf16(kc3, qf[a], z, 0, 0, 0);

      float e0[4], e1[4], e2[4], e3[4];
#pragma unroll
      for (int r = 0; r < 4; ++r) {
        e0[r] = fexp2(S0[r]);
        e1[r] = fexp2(S1[r]);
        e2[r] = fexp2(S2[r]);
        e3[r] = fexp2(S3[r]);
      }
      union { bf16x8 v; unsigned u[4]; } pf0, pf1;
      pf0.u[0] = pk2(e0[0], e0[1]);
      pf0.u[1] = pk2(e0[2], e0[3]);
      pf0.u[2] = pk2(e1[0], e1[1]);
      pf0.u[3] = pk2(e1[2], e1[3]);
      pf1.u[0] = pk2(e2[0], e2[1]);
      pf1.u[1] = pk2(e2[2], e2[3]);
      pf1.u[2] = pk2(e3[0], e3[1]);
      pf1.u[3] = pk2(e3[2], e3[3]);

      O[a][0] = __builtin_amdgcn_mfma_f32_16x16x32_bf16(pf0.v, vc0, O[a][0], 0, 0, 0);
      O[a][1] = __builtin_amdgcn_mfma_f32_16x16x32_bf16(pf0.v, vc1, O[a][1], 0, 0, 0);
      lacc[a] = __builtin_amdgcn_mfma_f32_16x16x32_bf16(pf0.v, ones, lacc[a], 0, 0, 0);
      O[a][0] = __builtin_amdgcn_mfma_f32_16x16x32_bf16(pf1.v, vc2, O[a][0], 0, 0, 0);
      O[a][1] = __builtin_amdgcn_mfma_f32_16x16x32_bf16(pf1.v, vc3, O[a][1], 0, 0, 0);
      lacc[a] = __builtin_amdgcn_mfma_f32_16x16x32_bf16(pf1.v, ones, lacc[a], 0, 0, 0);
    }
  }

#pragma unroll
  for (int a = 0; a < 4; ++a)
#pragma unroll
    for (int r = 0; r < 4; ++r) {
      const int row = q0 + a * 16 + quad * 4 + r;
      short* op = Opart + ((size_t)split * 4096 + row) * 256 + head * 32 + m;
      op[0]  = f2bs(O[a][0][r]);
      op[16] = f2bs(O[a][1][r]);
      if (m == 0) lpart[(size_t)(split * 8 + head) * 4096 + row] = lacc[a][r];
    }
}

// ---------- host launch ----------
extern "C" void kernel_launch(void* const* d_in, const int* in_sizes, int n_in,
                              void* d_out, int out_size, void* d_ws, size_t ws_size,
                              hipStream_t stream) {
  const int* edge = (const int*)d_in[0];
  const int* tgt = edge + NE;

  float* ws = (float*)d_ws;
  float* hbuf   = ws;                        // 1048576
  float* rbuf   = ws + 1048576;              // 1048576
  int* cnt      = (int*)(ws + 2097152);      // 1024
  int* inv      = cnt + 1024;                // 8192
  float* prm    = ws + 2360320;              // 7424 fp32 params
  short* xn_bf  = (short*)(ws + 2367744);    // 1048576 sh
  short* t_bf   = (short*)(ws + 2892032);    // 1048576 sh (out -> up)
  short* Wt     = (short*)(ws + 3416320);    // 1064960 sh
  short* Qh     = (short*)(ws + 3948800);    // 1048576 sh
  short* Kh     = (short*)(ws + 4473088);
  short* Vt     = (short*)(ws + 4997376);
  float* lpart  = ws + 5521664;              // 131072
  float* BIG    = ws + 5652736;              // 4194304 (aliased)
  int* flag     = (int*)(ws + 9847040);

  // BIG aliases (phase-disjoint):
  short* e1_bf   = (short*)(BIG + 131072);   // embed
  short* Opart   = (short*)BIG;              // flash -> fused out GEMM (bf16)

  const short* Wt_emb = Wt;
  const short* Wt_h   = Wt + 16384;
  const short* Wt_in  = Wt + 81920;
  const short* Wt_out = Wt + 671744;
  const short* Wt_up  = Wt + 868352;
  const float* b_emb = prm;
  const float* b_h   = prm + 256;
  const float* ln1_g = prm + 512;
  const float* ln1_b = prm + 1280;
  const float* in_b  = prm + 2048;
  const float* out_b = prm + 4352;
  const float* up_b  = prm + 5120;
  const float* ln2_g = prm + 5888;
  const float* ln2_b = prm + 6656;

  k_detect<<<dim3(1), dim3(64), 0, stream>>>((const unsigned*)d_in[2], flag, cnt);
  WPtrs wp = {d_in[2], d_in[4], d_in[8], d_in[10], d_in[12]};
  PPtrs pp = {{d_in[3], d_in[5], d_in[6], d_in[7], d_in[9], d_in[11],
               d_in[13], d_in[14], d_in[15]}};
  k_prep<<<dim3(4205), dim3(256), 0, stream>>>(wp, pp, tgt, Wt, prm, cnt, inv,
                                               flag);

  dim3 blk(256);
  dim3 g256(64, 4);
  dim3 g768(64, 12);
  dim3 gfa(16, 8, 4);

  // embed: e1 = gelu(bond @ W_emb + b_emb)  [bond read raw, dtype-probed]
  k_mgemm<64, true, true, false, true><<<g256, blk, 0, stream>>>(
      (const short*)d_in[1], Wt_emb, b_emb, nullptr, e1_bf, flag, NE, 256);
  // h = e1 @ W_h + b_h
  k_mgemm<256, false, false, true, false><<<g256, blk, 0, stream>>>(
      e1_bf, Wt_h, b_h, hbuf, nullptr, nullptr, NE, 256);

  for (int t = 0; t < 3; ++t) {
    k_rln2<<<dim3(NE), blk, 0, stream>>>(tgt, cnt, inv, hbuf,
                                         ln1_g + t * HDIM, ln1_b + t * HDIM,
                                         rbuf, xn_bf);
    k_mgemm_qkv<<<g768, blk, 0, stream>>>(xn_bf, Wt_in + (size_t)t * 196608,
                                          in_b + t * 768, Qh, Kh, Vt);
    k_flash4<<<gfa, blk, 0, stream>>>(Qh, Kh, Vt, Opart, lpart);
    // t_ij = merge(Opart,lpart) @ Wt_out^T + out_b + 2*r   (merge fused)
    k_mgemm_out<<<g256, blk, 0, stream>>>(Opart, lpart,
                                          Wt_out + (size_t)t * 65536,
                                          out_b + t * 256, rbuf, t_bf);
    // h = gelu(LN(t_ij @ Wt_up^T + up_b))   (ln_gelu fused)
    k_up_ln<<<dim3(256), blk, 0, stream>>>(t_bf, Wt_up + (size_t)t * 65536,
                                           up_b + t * 256, ln2_g + t * HDIM,
                                           ln2_b + t * HDIM, hbuf,
                                           (t == 2) ? d_out : nullptr, flag);
  }
}

// Round 14
// 286.955 us; speedup vs baseline: 1.0945x; 1.0945x over previous
//
#include <hip/hip_runtime.h>
#include <hip/hip_bf16.h>
#include <math.h>

#define N_NODES 1024
#define NE      4096
#define HDIM    256
// SCALE * log2(e) folded into Q: scores come out in log2 units
#define QSCALE  0.2550348634f

typedef __hip_bfloat16 bf16;
typedef __attribute__((ext_vector_type(8))) short bf16x8;
typedef __attribute__((ext_vector_type(4))) float f32x4;

__device__ __forceinline__ float u2f(unsigned short u) {
  return __uint_as_float(((unsigned)u) << 16);
}
__device__ __forceinline__ short f2bs(float x) {  // fp32 -> bf16 bits, RNE
  unsigned u = __float_as_uint(x);
  unsigned r = u + 0x7FFFu + ((u >> 16) & 1u);
  return (short)(r >> 16);
}
__device__ __forceinline__ float gelu_f(float x) {
  return 0.5f * x * (1.0f + erff(x * 0.70710678118654752f));
}
__device__ __forceinline__ short rdbf(const void* p, int i, int flag) {
  return flag ? ((const short*)p)[i] : f2bs(((const float*)p)[i]);
}
__device__ __forceinline__ float fexp2(float x) {
#if __has_builtin(__builtin_amdgcn_exp2f)
  return __builtin_amdgcn_exp2f(x);
#else
  return exp2f(x);
#endif
}
// pack two fp32 into (hi<<16)|(lo) bf16 pair, truncating (v4-validated)
__device__ __forceinline__ unsigned pk2(float lo, float hi) {
  return (__float_as_uint(hi) & 0xFFFF0000u) | (__float_as_uint(lo) >> 16);
}
// RNE pack of two fp32 into bf16 pair
__device__ __forceinline__ unsigned pk2r(float lo, float hi) {
  return (unsigned)(unsigned short)f2bs(lo) |
         ((unsigned)(unsigned short)f2bs(hi) << 16);
}

// ---------- dtype probe + cnt zero ----------
__global__ __launch_bounds__(64) void k_detect(const unsigned* __restrict__ w,
                                               int* __restrict__ flag,
                                               int* __restrict__ cnt) {
  int t = threadIdx.x;
  int c = 0;
  for (int i = 0; i < 16; ++i) {
    unsigned v = w[t * 16 + i];
    unsigned e = (v >> 7) & 0xFFu;
    c += (e >= 100u && e <= 132u) ? 1 : 0;
  }
#pragma unroll
  for (int k = 1; k < 64; k <<= 1) c += __shfl_xor(c, k, 64);
  if (t == 0) *flag = (c > 512) ? 1 : 0;  // 1 = bf16, 0 = fp32
#pragma unroll
  for (int j = 0; j < 16; ++j) cnt[t * 16 + j] = 0;
}

// ---------- merged prologue: weights + small params + inverse edges ----------
struct WPtrs { const void* w_emb; const void* w_h; const void* in_w;
               const void* out_w; const void* up_w; };
struct PPtrs { const void* p[9]; };
__global__ __launch_bounds__(256) void k_prep(WPtrs a, PPtrs pp,
                                              const int* __restrict__ tgt,
                                              short* __restrict__ Wt,
                                              float* __restrict__ prm,
                                              int* __restrict__ cnt,
                                              int* __restrict__ inv,
                                              const int* __restrict__ flag) {
  int i = blockIdx.x * 256 + threadIdx.x;
  const int fl = *flag;
  if (i < 1064960) {
    if (i < 16384) {                       // W_emb [64][256]
      int k = i >> 8, n = i & 255;
      Wt[n * 64 + k] = rdbf(a.w_emb, i, fl);
    } else if (i < 81920) {                // W_h [256][256]
      int j = i - 16384;
      int k = j >> 8, n = j & 255;
      Wt[16384 + n * 256 + k] = rdbf(a.w_h, j, fl);
    } else if (i < 671744) {               // in_w [3][256][768]
      int j = i - 81920;
      int t = j / 196608, jj = j % 196608;
      int k = jj / 768, n = jj % 768;
      Wt[81920 + t * 196608 + n * 256 + k] = rdbf(a.in_w, j, fl);
    } else if (i < 868352) {               // out_w [3][256][256]
      int j = i - 671744;
      int t = j >> 16, jj = j & 65535;
      int k = jj >> 8, n = jj & 255;
      Wt[671744 + t * 65536 + n * 256 + k] = rdbf(a.out_w, j, fl);
    } else {                               // up_w [3][256][256]
      int j = i - 868352;
      int t = j >> 16, jj = j & 65535;
      int k = jj >> 8, n = jj & 255;
      Wt[868352 + t * 65536 + n * 256 + k] = rdbf(a.up_w, j, fl);
    }
  } else if (i < 1072384) {                // small params -> fp32
    int j = i - 1064960;
    const int sz[9] = {256, 256, 768, 768, 2304, 768, 768, 768, 768};
    int seg = 0, off = j;
    while (off >= sz[seg]) { off -= sz[seg]; ++seg; }
    prm[j] = fl ? u2f(((const unsigned short*)pp.p[seg])[off])
                : ((const float*)pp.p[seg])[off];
  } else if (i < 1076480) {                // inverse edge list
    int e = i - 1072384;
    int t = tgt[e];
    int s = atomicAdd(&cnt[t], 1);
    if (s < 8) inv[t * 8 + s] = e;
  }
}

// ---------- MFMA GEMM: full-K LDS, ONE barrier, XOR-swizzled ----------
// C = epi(A[MxK]bf16 @ Wt[NxK]bf16^T + bias). RAW=true: A is the raw bond
// input (probed dtype) -- fuses the bond conversion.
template <int K, bool RAW, bool GELU, bool WF, bool WB>
__global__ __launch_bounds__(256) void k_mgemm(const short* __restrict__ A,
                                               const short* __restrict__ Bt,
                                               const float* __restrict__ bias,
                                               float* __restrict__ outF,
                                               short* __restrict__ outB,
                                               const int* __restrict__ flag,
                                               int M, int N) {
  __shared__ alignas(16) short As[64 * K];
  __shared__ alignas(16) short Bs[64 * K];
  const int tid = threadIdx.x;
  const int wave = tid >> 6, lane = tid & 63;
  const int m = lane & 15, quad = lane >> 4;
  const int bm = blockIdx.x * 64, bn = blockIdx.y * 64;
  const int m0 = (wave & 1) * 32, n0 = (wave >> 1) * 32;

  constexpr int CPR = K >> 3;
  constexpr int CPT = K >> 5;

  const int fl = RAW ? *flag : 1;

  int4 ra[CPT], rb[CPT];
#pragma unroll
  for (int i = 0; i < CPT; ++i) {
    const int c = tid + (i << 8);
    const int row = c / CPR, kc = c % CPR;
    if (RAW && !fl) {
      const float* af = (const float*)A + (size_t)(bm + row) * K + kc * 8;
      unsigned* vu = (unsigned*)&ra[i];
      vu[0] = pk2r(af[0], af[1]);
      vu[1] = pk2r(af[2], af[3]);
      vu[2] = pk2r(af[4], af[5]);
      vu[3] = pk2r(af[6], af[7]);
    } else {
      ra[i] = *(const int4*)(A + (size_t)(bm + row) * K + kc * 8);
    }
    rb[i] = *(const int4*)(Bt + (size_t)(bn + row) * K + kc * 8);
  }
#pragma unroll
  for (int i = 0; i < CPT; ++i) {
    const int c = tid + (i << 8);
    const int row = c / CPR, kc = c % CPR;
    *(int4*)&As[row * K + ((kc ^ (row & 7)) << 3)] = ra[i];
    *(int4*)&Bs[row * K + ((kc ^ (row & 7)) << 3)] = rb[i];
  }
  __syncthreads();

  f32x4 acc[2][2];
  acc[0][0] = acc[0][1] = acc[1][0] = acc[1][1] = (f32x4){0.f, 0.f, 0.f, 0.f};

  const int sw = m & 7;
#pragma unroll
  for (int ks = 0; ks < K / 32; ++ks) {
    const int ca = ((ks * 4 + quad) ^ sw) << 3;
    bf16x8 a0 = *(const bf16x8*)&As[(m0 + m) * K + ca];
    bf16x8 a1 = *(const bf16x8*)&As[(m0 + 16 + m) * K + ca];
    bf16x8 b0 = *(const bf16x8*)&Bs[(n0 + m) * K + ca];
    bf16x8 b1 = *(const bf16x8*)&Bs[(n0 + 16 + m) * K + ca];
    acc[0][0] = __builtin_amdgcn_mfma_f32_16x16x32_bf16(a0, b0, acc[0][0], 0, 0, 0);
    acc[0][1] = __builtin_amdgcn_mfma_f32_16x16x32_bf16(a0, b1, acc[0][1], 0, 0, 0);
    acc[1][0] = __builtin_amdgcn_mfma_f32_16x16x32_bf16(a1, b0, acc[1][0], 0, 0, 0);
    acc[1][1] = __builtin_amdgcn_mfma_f32_16x16x32_bf16(a1, b1, acc[1][1], 0, 0, 0);
  }

#pragma unroll
  for (int i = 0; i < 2; ++i)
#pragma unroll
    for (int j = 0; j < 2; ++j) {
      const int col = bn + n0 + j * 16 + m;
      const float bv = bias[col];
#pragma unroll
      for (int r = 0; r < 4; ++r) {
        const int row = bm + m0 + i * 16 + quad * 4 + r;
        float v = acc[i][j][r] + bv;
        if (GELU) v = gelu_f(v);
        if (WF) outF[(size_t)row * N + col] = v;
        if (WB) outB[(size_t)row * N + col] = f2bs(v);
      }
    }
}

// out-projection GEMM with FUSED split-merge (deletes k_merge):
// t_ij = (merge(Opart,lpart)) @ Wt_out^T + bias + 2*r, written bf16.
__global__ __launch_bounds__(256) void k_mgemm_out(const short* __restrict__ Opart,
                                                   const float* __restrict__ lpart,
                                                   const short* __restrict__ Bt,
                                                   const float* __restrict__ bias,
                                                   const float* __restrict__ res,
                                                   short* __restrict__ outB) {
  constexpr int K = 256;
  __shared__ alignas(16) short As[64 * K];
  __shared__ alignas(16) short Bs[64 * K];
  const int tid = threadIdx.x;
  const int wave = tid >> 6, lane = tid & 63;
  const int m = lane & 15, quad = lane >> 4;
  const int bm = blockIdx.x * 64, bn = blockIdx.y * 64;
  const int m0 = (wave & 1) * 32, n0 = (wave >> 1) * 32;

  int4 ra[8], rb[8];
#pragma unroll
  for (int i = 0; i < 8; ++i) {
    const int c = tid + (i << 8);
    const int row = c >> 5, kc = c & 31;
    const int R = bm + row, head = kc >> 2;
    float o[8] = {0.f, 0.f, 0.f, 0.f, 0.f, 0.f, 0.f, 0.f};
    float l = 0.f;
#pragma unroll
    for (int s = 0; s < 4; ++s) {
      int4 ov = *(const int4*)(Opart + (size_t)s * 1048576 + (size_t)R * 256 + kc * 8);
      const unsigned short* os = (const unsigned short*)&ov;
#pragma unroll
      for (int j = 0; j < 8; ++j) o[j] += u2f(os[j]);
      l += lpart[(size_t)(s * 8 + head) * 4096 + R];
    }
    const float inv = 1.0f / l;
    unsigned* vu = (unsigned*)&ra[i];
    vu[0] = pk2r(o[0] * inv, o[1] * inv);
    vu[1] = pk2r(o[2] * inv, o[3] * inv);
    vu[2] = pk2r(o[4] * inv, o[5] * inv);
    vu[3] = pk2r(o[6] * inv, o[7] * inv);
    rb[i] = *(const int4*)(Bt + (size_t)(bn + row) * K + kc * 8);
  }
#pragma unroll
  for (int i = 0; i < 8; ++i) {
    const int c = tid + (i << 8);
    const int row = c >> 5, kc = c & 31;
    *(int4*)&As[row * K + ((kc ^ (row & 7)) << 3)] = ra[i];
    *(int4*)&Bs[row * K + ((kc ^ (row & 7)) << 3)] = rb[i];
  }
  __syncthreads();

  f32x4 acc[2][2];
  acc[0][0] = acc[0][1] = acc[1][0] = acc[1][1] = (f32x4){0.f, 0.f, 0.f, 0.f};

  const int sw = m & 7;
#pragma unroll
  for (int ks = 0; ks < K / 32; ++ks) {
    const int ca = ((ks * 4 + quad) ^ sw) << 3;
    bf16x8 a0 = *(const bf16x8*)&As[(m0 + m) * K + ca];
    bf16x8 a1 = *(const bf16x8*)&As[(m0 + 16 + m) * K + ca];
    bf16x8 b0 = *(const bf16x8*)&Bs[(n0 + m) * K + ca];
    bf16x8 b1 = *(const bf16x8*)&Bs[(n0 + 16 + m) * K + ca];
    acc[0][0] = __builtin_amdgcn_mfma_f32_16x16x32_bf16(a0, b0, acc[0][0], 0, 0, 0);
    acc[0][1] = __builtin_amdgcn_mfma_f32_16x16x32_bf16(a0, b1, acc[0][1], 0, 0, 0);
    acc[1][0] = __builtin_amdgcn_mfma_f32_16x16x32_bf16(a1, b0, acc[1][0], 0, 0, 0);
    acc[1][1] = __builtin_amdgcn_mfma_f32_16x16x32_bf16(a1, b1, acc[1][1], 0, 0, 0);
  }

#pragma unroll
  for (int i = 0; i < 2; ++i)
#pragma unroll
    for (int j = 0; j < 2; ++j) {
      const int col = bn + n0 + j * 16 + m;
      const float bv = bias[col];
#pragma unroll
      for (int r = 0; r < 4; ++r) {
        const int row = bm + m0 + i * 16 + quad * 4 + r;
        float v = acc[i][j][r] + bv + 2.0f * res[(size_t)row * 256 + col];
        outB[(size_t)row * 256 + col] = f2bs(v);
      }
    }
}

// qkv variant (K=256, full-K single-barrier staging): writes
// Qh/Kh[head][4096][32] (Q pre-scaled, K linear), Vt[head][32][4096] with
// the in-tile key PERMUTATION baked in:
//   key T -> (T&~63) + ((T>>5)&1)*32 + ((T>>2)&3)*8 + ((T>>4)&1)*4 + (T&3)
// so flash's PV A-fragment needs no LDS round-trip.
__global__ __launch_bounds__(256) void k_mgemm_qkv(const short* __restrict__ A,
                                                   const short* __restrict__ Bt,
                                                   const float* __restrict__ bias,
                                                   short* __restrict__ Qh,
                                                   short* __restrict__ Kh,
                                                   short* __restrict__ Vt) {
  constexpr int K = 256;
  __shared__ alignas(16) short As[64 * K];
  __shared__ alignas(16) short Bs[64 * K];
  const int tid = threadIdx.x;
  const int wave = tid >> 6, lane = tid & 63;
  const int m = lane & 15, quad = lane >> 4;
  const int bm = blockIdx.x * 64, bn = blockIdx.y * 64;
  const int m0 = (wave & 1) * 32, n0 = (wave >> 1) * 32;

  int4 ra[8], rb[8];
#pragma unroll
  for (int i = 0; i < 8; ++i) {
    const int c = tid + (i << 8);
    const int row = c >> 5, kc = c & 31;
    ra[i] = *(const int4*)(A + (size_t)(bm + row) * K + kc * 8);
    rb[i] = *(const int4*)(Bt + (size_t)(bn + row) * K + kc * 8);
  }
#pragma unroll
  for (int i = 0; i < 8; ++i) {
    const int c = tid + (i << 8);
    const int row = c >> 5, kc = c & 31;
    *(int4*)&As[row * K + ((kc ^ (row & 7)) << 3)] = ra[i];
    *(int4*)&Bs[row * K + ((kc ^ (row & 7)) << 3)] = rb[i];
  }
  __syncthreads();

  f32x4 acc[2][2];
  acc[0][0] = acc[0][1] = acc[1][0] = acc[1][1] = (f32x4){0.f, 0.f, 0.f, 0.f};

  const int sw = m & 7;
#pragma unroll
  for (int ks = 0; ks < K / 32; ++ks) {
    const int ca = ((ks * 4 + quad) ^ sw) << 3;
    bf16x8 a0 = *(const bf16x8*)&As[(m0 + m) * K + ca];
    bf16x8 a1 = *(const bf16x8*)&As[(m0 + 16 + m) * K + ca];
    bf16x8 b0 = *(const bf16x8*)&Bs[(n0 + m) * K + ca];
    bf16x8 b1 = *(const bf16x8*)&Bs[(n0 + 16 + m) * K + ca];
    acc[0][0] = __builtin_amdgcn_mfma_f32_16x16x32_bf16(a0, b0, acc[0][0], 0, 0, 0);
    acc[0][1] = __builtin_amdgcn_mfma_f32_16x16x32_bf16(a0, b1, acc[0][1], 0, 0, 0);
    acc[1][0] = __builtin_amdgcn_mfma_f32_16x16x32_bf16(a1, b0, acc[1][0], 0, 0, 0);
    acc[1][1] = __builtin_amdgcn_mfma_f32_16x16x32_bf16(a1, b1, acc[1][1], 0, 0, 0);
  }

#pragma unroll
  for (int i = 0; i < 2; ++i)
#pragma unroll
    for (int j = 0; j < 2; ++j) {
      const int col = bn + n0 + j * 16 + m;
      const float bv = bias[col];
      const int row0 = bm + m0 + i * 16 + quad * 4;
      if (col < 256) {
        const int head = col >> 5, d = col & 31;
#pragma unroll
        for (int r = 0; r < 4; ++r)
          Qh[(size_t)head * 131072 + (row0 + r) * 32 + d] =
              f2bs((acc[i][j][r] + bv) * QSCALE);
      } else if (col < 512) {
        const int c = col - 256, head = c >> 5, d = c & 31;
#pragma unroll
        for (int r = 0; r < 4; ++r)
          Kh[(size_t)head * 131072 + (row0 + r) * 32 + d] = f2bs(acc[i][j][r] + bv);
      } else {
        const int c = col - 512, head = c >> 5, d = c & 31;
        const int p0 = (row0 & ~63) + ((row0 >> 5) & 1) * 32 +
                       ((row0 >> 2) & 3) * 8 + ((row0 >> 4) & 1) * 4;
        ushort4 w;
        w.x = (unsigned short)f2bs(acc[i][j][0] + bv);
        w.y = (unsigned short)f2bs(acc[i][j][1] + bv);
        w.z = (unsigned short)f2bs(acc[i][j][2] + bv);
        w.w = (unsigned short)f2bs(acc[i][j][3] + bv);
        *(ushort4*)(Vt + (size_t)head * 131072 + d * 4096 + p0) = w;
      }
    }
}

// ---------- fused gather-aggregation + LN ----------
__global__ __launch_bounds__(256) void k_rln2(const int* __restrict__ tgt,
                                              const int* __restrict__ cnt,
                                              const int* __restrict__ inv,
                                              const float* __restrict__ h,
                                              const float* __restrict__ g,
                                              const float* __restrict__ b,
                                              float* __restrict__ r,
                                              short* __restrict__ xnb) {
  __shared__ float red1[4], red2[4];
  const int e = blockIdx.x, d = threadIdx.x;
  const int t = tgt[e];
  const int c = cnt[t];
  float S = 0.f;
  for (int j = 0; j < c; ++j)
    S += h[(size_t)inv[t * 8 + j] * HDIM + d];
  float rv = S - (float)c * h[(size_t)e * HDIM + d];
  r[(size_t)e * HDIM + d] = rv;

  float s = rv;
#pragma unroll
  for (int k = 1; k < 64; k <<= 1) s += __shfl_xor(s, k, 64);
  if ((d & 63) == 0) red1[d >> 6] = s;
  __syncthreads();
  float mean = (red1[0] + red1[1] + red1[2] + red1[3]) * (1.0f / HDIM);
  float diff = rv - mean;
  float sq = diff * diff;
#pragma unroll
  for (int k = 1; k < 64; k <<= 1) sq += __shfl_xor(sq, k, 64);
  if ((d & 63) == 0) red2[d >> 6] = sq;
  __syncthreads();
  float var = (red2[0] + red2[1] + red2[2] + red2[3]) * (1.0f / HDIM);
  xnb[(size_t)e * HDIM + d] = f2bs(diff * rsqrtf(var + 1e-5f) * g[d] + b[d]);
}

// h = gelu(LN(u)*g + b); final layer also stores to d_out in probed dtype
__global__ __launch_bounds__(256) void k_ln_gelu(const float* __restrict__ u,
                                                 const float* __restrict__ g,
                                                 const float* __restrict__ b,
                                                 float* __restrict__ hout,
                                                 void* __restrict__ finalout,
                                                 const int* __restrict__ flag) {
  __shared__ float red1[4], red2[4];
  const int e = blockIdx.x, d = threadIdx.x;
  float v = u[(size_t)e * HDIM + d];
  float s = v;
#pragma unroll
  for (int k = 1; k < 64; k <<= 1) s += __shfl_xor(s, k, 64);
  if ((d & 63) == 0) red1[d >> 6] = s;
  __syncthreads();
  float mean = (red1[0] + red1[1] + red1[2] + red1[3]) * (1.0f / HDIM);
  float diff = v - mean;
  float sq = diff * diff;
#pragma unroll
  for (int k = 1; k < 64; k <<= 1) sq += __shfl_xor(sq, k, 64);
  if ((d & 63) == 0) red2[d >> 6] = sq;
  __syncthreads();
  float var = (red2[0] + red2[1] + red2[2] + red2[3]) * (1.0f / HDIM);
  float xh = diff * rsqrtf(var + 1e-5f) * g[d] + b[d];
  float out = gelu_f(xh);
  hout[(size_t)e * HDIM + d] = out;
  if (finalout) {
    if (*flag)
      ((bf16*)finalout)[(size_t)e * HDIM + d] = __float2bfloat16(out);
    else
      ((float*)finalout)[(size_t)e * HDIM + d] = out;
  }
}

// ---------- MFMA flash attention v13: LDS-shared K/V, 64 q/wave ----------
__global__ __launch_bounds__(256) void k_flash4(const short* __restrict__ Qh,
                                                const short* __restrict__ Kh,
                                                const short* __restrict__ Vt,
                                                short* __restrict__ Opart,
                                                float* __restrict__ lpart) {
  __shared__ alignas(16) short Ks[64 * 40];
  __shared__ alignas(16) short Vs[32 * 70 + 8];
  const int head = blockIdx.y, split = blockIdx.z;
  const int tid = threadIdx.x;
  const int wave = tid >> 6, lane = tid & 63;
  const int m = lane & 15, quad = lane >> 4;
  const int q0 = blockIdx.x * 256 + wave * 64;

  const short* Qb = Qh + (size_t)head * 131072;
  const short* Kb = Kh + (size_t)head * 131072;
  const short* Vb = Vt + (size_t)head * 131072;

  bf16x8 qf[4];
#pragma unroll
  for (int a = 0; a < 4; ++a)
    qf[a] = *(const bf16x8*)(Qb + (q0 + a * 16 + m) * 32 + quad * 8);

  f32x4 O[4][2];
  f32x4 lacc[4];
#pragma unroll
  for (int a = 0; a < 4; ++a) {
    O[a][0] = O[a][1] = (f32x4){0.f, 0.f, 0.f, 0.f};
    lacc[a] = (f32x4){0.f, 0.f, 0.f, 0.f};
  }

  bf16x8 ones;
#pragma unroll
  for (int i = 0; i < 8; ++i) ones[i] = (short)0x3F80;  // bf16 1.0

  const int base = split * 1024;
  const int krow = tid >> 2, ko = (tid & 3) * 8;
  const int vrow = tid >> 3, vo = (tid & 7) * 8;
  const short* kstage = Kb + (size_t)(base + krow) * 32 + ko;   // + kb*2048
  const short* vstage = Vb + (size_t)vrow * 4096 + base + vo;   // + kb*64

  int4 rk = *(const int4*)(kstage);
  int4 rv = *(const int4*)(vstage);

#pragma unroll 1
  for (int kb = 0; kb < 16; ++kb) {
    __syncthreads();
    *(int4*)&Ks[krow * 40 + ko] = rk;
    *(int4*)&Vs[vrow * 70 + vo] = rv;
    __syncthreads();
    if (kb < 15) {
      rk = *(const int4*)(kstage + (kb + 1) * 2048);
      rv = *(const int4*)(vstage + (kb + 1) * 64);
    }

    bf16x8 kc0 = *(const bf16x8*)&Ks[(0 * 16 + m) * 40 + quad * 8];
    bf16x8 kc1 = *(const bf16x8*)&Ks[(1 * 16 + m) * 40 + quad * 8];
    bf16x8 kc2 = *(const bf16x8*)&Ks[(2 * 16 + m) * 40 + quad * 8];
    bf16x8 kc3 = *(const bf16x8*)&Ks[(3 * 16 + m) * 40 + quad * 8];
    bf16x8 vc0 = *(const bf16x8*)&Vs[m * 70 + quad * 8];
    bf16x8 vc1 = *(const bf16x8*)&Vs[(m + 16) * 70 + quad * 8];
    bf16x8 vc2 = *(const bf16x8*)&Vs[m * 70 + 32 + quad * 8];
    bf16x8 vc3 = *(const bf16x8*)&Vs[(m + 16) * 70 + 32 + quad * 8];

    const f32x4 z = {0.f, 0.f, 0.f, 0.f};
#pragma unroll
    for (int a = 0; a < 4; ++a) {
      f32x4 S0 = __builtin_amdgcn_mfma_f32_16x16x32_bf16(kc0, qf[a], z, 0, 0, 0);
      f32x4 S1 = __builtin_amdgcn_mfma_f32_16x16x32_bf16(kc1, qf[a], z, 0, 0, 0);
      f32x4 S2 = __builtin_amdgcn_mfma_f32_16x16x32_bf16(kc2, qf[a], z, 0, 0, 0);
      f32x4 S3 = __builtin_amdgcn_mfma_f32_16x16x32_bf16(kc3, qf[a], z, 0, 0, 0);

      float e0[4], e1[4], e2[4], e3[4];
#pragma unroll
      for (int r = 0; r < 4; ++r) {
        e0[r] = fexp2(S0[r]);
        e1[r] = fexp2(S1[r]);
        e2[r] = fexp2(S2[r]);
        e3[r] = fexp2(S3[r]);
      }
      union { bf16x8 v; unsigned u[4]; } pf0, pf1;
      pf0.u[0] = pk2(e0[0], e0[1]);
      pf0.u[1] = pk2(e0[2], e0[3]);
      pf0.u[2] = pk2(e1[0], e1[1]);
      pf0.u[3] = pk2(e1[2], e1[3]);
      pf1.u[0] = pk2(e2[0], e2[1]);
      pf1.u[1] = pk2(e2[2], e2[3]);
      pf1.u[2] = pk2(e3[0], e3[1]);
      pf1.u[3] = pk2(e3[2], e3[3]);

      O[a][0] = __builtin_amdgcn_mfma_f32_16x16x32_bf16(pf0.v, vc0, O[a][0], 0, 0, 0);
      O[a][1] = __builtin_amdgcn_mfma_f32_16x16x32_bf16(pf0.v, vc1, O[a][1], 0, 0, 0);
      lacc[a] = __builtin_amdgcn_mfma_f32_16x16x32_bf16(pf0.v, ones, lacc[a], 0, 0, 0);
      O[a][0] = __builtin_amdgcn_mfma_f32_16x16x32_bf16(pf1.v, vc2, O[a][0], 0, 0, 0);
      O[a][1] = __builtin_amdgcn_mfma_f32_16x16x32_bf16(pf1.v, vc3, O[a][1], 0, 0, 0);
      lacc[a] = __builtin_amdgcn_mfma_f32_16x16x32_bf16(pf1.v, ones, lacc[a], 0, 0, 0);
    }
  }

#pragma unroll
  for (int a = 0; a < 4; ++a)
#pragma unroll
    for (int r = 0; r < 4; ++r) {
      const int row = q0 + a * 16 + quad * 4 + r;
      short* op = Opart + ((size_t)split * 4096 + row) * 256 + head * 32 + m;
      op[0]  = f2bs(O[a][0][r]);
      op[16] = f2bs(O[a][1][r]);
      if (m == 0) lpart[(size_t)(split * 8 + head) * 4096 + row] = lacc[a][r];
    }
}

// ---------- host launch ----------
extern "C" void kernel_launch(void* const* d_in, const int* in_sizes, int n_in,
                              void* d_out, int out_size, void* d_ws, size_t ws_size,
                              hipStream_t stream) {
  const int* edge = (const int*)d_in[0];
  const int* tgt = edge + NE;

  float* ws = (float*)d_ws;
  float* hbuf   = ws;                        // 1048576
  float* rbuf   = ws + 1048576;              // 1048576
  int* cnt      = (int*)(ws + 2097152);      // 1024
  int* inv      = cnt + 1024;                // 8192
  float* prm    = ws + 2360320;              // 7424 fp32 params
  short* xn_bf  = (short*)(ws + 2367744);    // 1048576 sh
  short* t_bf   = (short*)(ws + 2892032);    // 1048576 sh (out -> up)
  short* Wt     = (short*)(ws + 3416320);    // 1064960 sh
  short* Qh     = (short*)(ws + 3948800);    // 1048576 sh
  short* Kh     = (short*)(ws + 4473088);
  short* Vt     = (short*)(ws + 4997376);
  float* lpart  = ws + 5521664;              // 131072
  float* BIG    = ws + 5652736;              // 4194304 (aliased)
  int* flag     = (int*)(ws + 9847040);

  // BIG aliases (phase-disjoint):
  short* e1_bf   = (short*)(BIG + 131072);   // embed
  short* Opart   = (short*)BIG;              // flash -> fused out GEMM (bf16)
  float* ubuf    = BIG + 524288;             // up -> ln_gelu (Opart dead by then)

  const short* Wt_emb = Wt;
  const short* Wt_h   = Wt + 16384;
  const short* Wt_in  = Wt + 81920;
  const short* Wt_out = Wt + 671744;
  const short* Wt_up  = Wt + 868352;
  const float* b_emb = prm;
  const float* b_h   = prm + 256;
  const float* ln1_g = prm + 512;
  const float* ln1_b = prm + 1280;
  const float* in_b  = prm + 2048;
  const float* out_b = prm + 4352;
  const float* up_b  = prm + 5120;
  const float* ln2_g = prm + 5888;
  const float* ln2_b = prm + 6656;

  k_detect<<<dim3(1), dim3(64), 0, stream>>>((const unsigned*)d_in[2], flag, cnt);
  WPtrs wp = {d_in[2], d_in[4], d_in[8], d_in[10], d_in[12]};
  PPtrs pp = {{d_in[3], d_in[5], d_in[6], d_in[7], d_in[9], d_in[11],
               d_in[13], d_in[14], d_in[15]}};
  k_prep<<<dim3(4205), dim3(256), 0, stream>>>(wp, pp, tgt, Wt, prm, cnt, inv,
                                               flag);

  dim3 blk(256);
  dim3 g256(64, 4);
  dim3 g768(64, 12);
  dim3 gfa(16, 8, 4);

  // embed: e1 = gelu(bond @ W_emb + b_emb)  [bond read raw, dtype-probed]
  k_mgemm<64, true, true, false, true><<<g256, blk, 0, stream>>>(
      (const short*)d_in[1], Wt_emb, b_emb, nullptr, e1_bf, flag, NE, 256);
  // h = e1 @ W_h + b_h
  k_mgemm<256, false, false, true, false><<<g256, blk, 0, stream>>>(
      e1_bf, Wt_h, b_h, hbuf, nullptr, nullptr, NE, 256);

  for (int t = 0; t < 3; ++t) {
    k_rln2<<<dim3(NE), blk, 0, stream>>>(tgt, cnt, inv, hbuf,
                                         ln1_g + t * HDIM, ln1_b + t * HDIM,
                                         rbuf, xn_bf);
    k_mgemm_qkv<<<g768, blk, 0, stream>>>(xn_bf, Wt_in + (size_t)t * 196608,
                                          in_b + t * 768, Qh, Kh, Vt);
    k_flash4<<<gfa, blk, 0, stream>>>(Qh, Kh, Vt, Opart, lpart);
    // t_ij = merge(Opart,lpart) @ Wt_out^T + out_b + 2*r   (merge fused)
    k_mgemm_out<<<g256, blk, 0, stream>>>(Opart, lpart,
                                          Wt_out + (size_t)t * 65536,
                                          out_b + t * 256, rbuf, t_bf);
    // u = t_ij @ Wt_up^T + up_b
    k_mgemm<256, false, false, true, false><<<g256, blk, 0, stream>>>(
        t_bf, Wt_up + (size_t)t * 65536, up_b + t * 256, ubuf, nullptr,
        nullptr, NE, 256);
    k_ln_gelu<<<dim3(NE), blk, 0, stream>>>(ubuf, ln2_g + t * HDIM,
                                            ln2_b + t * HDIM, hbuf,
                                            (t == 2) ? d_out : nullptr, flag);
  }
}

// Round 15
// 286.568 us; speedup vs baseline: 1.0960x; 1.0014x over previous
//
#include <hip/hip_runtime.h>
#include <hip/hip_bf16.h>
#include <math.h>

#define N_NODES 1024
#define NE      4096
#define HDIM    256
// SCALE * log2(e) folded into Q: scores come out in log2 units
#define QSCALE  0.2550348634f

typedef __hip_bfloat16 bf16;
typedef __attribute__((ext_vector_type(8))) short bf16x8;
typedef __attribute__((ext_vector_type(4))) float f32x4;

__device__ __forceinline__ float u2f(unsigned short u) {
  return __uint_as_float(((unsigned)u) << 16);
}
__device__ __forceinline__ short f2bs(float x) {  // fp32 -> bf16 bits, RNE
  unsigned u = __float_as_uint(x);
  unsigned r = u + 0x7FFFu + ((u >> 16) & 1u);
  return (short)(r >> 16);
}
__device__ __forceinline__ float gelu_f(float x) {
  return 0.5f * x * (1.0f + erff(x * 0.70710678118654752f));
}
__device__ __forceinline__ short rdbf(const void* p, int i, int flag) {
  return flag ? ((const short*)p)[i] : f2bs(((const float*)p)[i]);
}
__device__ __forceinline__ float fexp2(float x) {
#if __has_builtin(__builtin_amdgcn_exp2f)
  return __builtin_amdgcn_exp2f(x);
#else
  return exp2f(x);
#endif
}
// pack two fp32 into (hi<<16)|(lo) bf16 pair, truncating (v4-validated)
__device__ __forceinline__ unsigned pk2(float lo, float hi) {
  return (__float_as_uint(hi) & 0xFFFF0000u) | (__float_as_uint(lo) >> 16);
}
// RNE pack of two fp32 into bf16 pair
__device__ __forceinline__ unsigned pk2r(float lo, float hi) {
  return (unsigned)(unsigned short)f2bs(lo) |
         ((unsigned)(unsigned short)f2bs(hi) << 16);
}

// ---------- dtype probe + cnt zero ----------
__global__ __launch_bounds__(64) void k_detect(const unsigned* __restrict__ w,
                                               int* __restrict__ flag,
                                               int* __restrict__ cnt) {
  int t = threadIdx.x;
  int c = 0;
  for (int i = 0; i < 16; ++i) {
    unsigned v = w[t * 16 + i];
    unsigned e = (v >> 7) & 0xFFu;
    c += (e >= 100u && e <= 132u) ? 1 : 0;
  }
#pragma unroll
  for (int k = 1; k < 64; k <<= 1) c += __shfl_xor(c, k, 64);
  if (t == 0) *flag = (c > 512) ? 1 : 0;  // 1 = bf16, 0 = fp32
#pragma unroll
  for (int j = 0; j < 16; ++j) cnt[t * 16 + j] = 0;
}

// ---------- merged prologue: weights + small params + inverse edges ----------
struct WPtrs { const void* w_emb; const void* w_h; const void* in_w;
               const void* out_w; const void* up_w; };
struct PPtrs { const void* p[9]; };
__global__ __launch_bounds__(256) void k_prep(WPtrs a, PPtrs pp,
                                              const int* __restrict__ tgt,
                                              short* __restrict__ Wt,
                                              float* __restrict__ prm,
                                              int* __restrict__ cnt,
                                              int* __restrict__ inv,
                                              const int* __restrict__ flag) {
  int i = blockIdx.x * 256 + threadIdx.x;
  const int fl = *flag;
  if (i < 1064960) {
    if (i < 16384) {                       // W_emb [64][256]
      int k = i >> 8, n = i & 255;
      Wt[n * 64 + k] = rdbf(a.w_emb, i, fl);
    } else if (i < 81920) {                // W_h [256][256]
      int j = i - 16384;
      int k = j >> 8, n = j & 255;
      Wt[16384 + n * 256 + k] = rdbf(a.w_h, j, fl);
    } else if (i < 671744) {               // in_w [3][256][768]
      int j = i - 81920;
      int t = j / 196608, jj = j % 196608;
      int k = jj / 768, n = jj % 768;
      Wt[81920 + t * 196608 + n * 256 + k] = rdbf(a.in_w, j, fl);
    } else if (i < 868352) {               // out_w [3][256][256]
      int j = i - 671744;
      int t = j >> 16, jj = j & 65535;
      int k = jj >> 8, n = jj & 255;
      Wt[671744 + t * 65536 + n * 256 + k] = rdbf(a.out_w, j, fl);
    } else {                               // up_w [3][256][256]
      int j = i - 868352;
      int t = j >> 16, jj = j & 65535;
      int k = jj >> 8, n = jj & 255;
      Wt[868352 + t * 65536 + n * 256 + k] = rdbf(a.up_w, j, fl);
    }
  } else if (i < 1072384) {                // small params -> fp32
    int j = i - 1064960;
    const int sz[9] = {256, 256, 768, 768, 2304, 768, 768, 768, 768};
    int seg = 0, off = j;
    while (off >= sz[seg]) { off -= sz[seg]; ++seg; }
    prm[j] = fl ? u2f(((const unsigned short*)pp.p[seg])[off])
                : ((const float*)pp.p[seg])[off];
  } else if (i < 1076480) {                // inverse edge list
    int e = i - 1072384;
    int t = tgt[e];
    int s = atomicAdd(&cnt[t], 1);
    if (s < 8) inv[t * 8 + s] = e;
  }
}

// ---------- MFMA GEMM: full-K LDS, ONE barrier, XOR-swizzled ----------
// C = epi(A[MxK]bf16 @ Wt[NxK]bf16^T + bias). RAW=true: A is the raw bond
// input (probed dtype) -- fuses the bond conversion.
template <int K, bool RAW, bool GELU, bool WF, bool WB>
__global__ __launch_bounds__(256) void k_mgemm(const short* __restrict__ A,
                                               const short* __restrict__ Bt,
                                               const float* __restrict__ bias,
                                               float* __restrict__ outF,
                                               short* __restrict__ outB,
                                               const int* __restrict__ flag,
                                               int M, int N) {
  __shared__ alignas(16) short As[64 * K];
  __shared__ alignas(16) short Bs[64 * K];
  const int tid = threadIdx.x;
  const int wave = tid >> 6, lane = tid & 63;
  const int m = lane & 15, quad = lane >> 4;
  const int bm = blockIdx.x * 64, bn = blockIdx.y * 64;
  const int m0 = (wave & 1) * 32, n0 = (wave >> 1) * 32;

  constexpr int CPR = K >> 3;
  constexpr int CPT = K >> 5;

  const int fl = RAW ? *flag : 1;

  int4 ra[CPT], rb[CPT];
#pragma unroll
  for (int i = 0; i < CPT; ++i) {
    const int c = tid + (i << 8);
    const int row = c / CPR, kc = c % CPR;
    if (RAW && !fl) {
      const float* af = (const float*)A + (size_t)(bm + row) * K + kc * 8;
      unsigned* vu = (unsigned*)&ra[i];
      vu[0] = pk2r(af[0], af[1]);
      vu[1] = pk2r(af[2], af[3]);
      vu[2] = pk2r(af[4], af[5]);
      vu[3] = pk2r(af[6], af[7]);
    } else {
      ra[i] = *(const int4*)(A + (size_t)(bm + row) * K + kc * 8);
    }
    rb[i] = *(const int4*)(Bt + (size_t)(bn + row) * K + kc * 8);
  }
#pragma unroll
  for (int i = 0; i < CPT; ++i) {
    const int c = tid + (i << 8);
    const int row = c / CPR, kc = c % CPR;
    *(int4*)&As[row * K + ((kc ^ (row & 7)) << 3)] = ra[i];
    *(int4*)&Bs[row * K + ((kc ^ (row & 7)) << 3)] = rb[i];
  }
  __syncthreads();

  f32x4 acc[2][2];
  acc[0][0] = acc[0][1] = acc[1][0] = acc[1][1] = (f32x4){0.f, 0.f, 0.f, 0.f};

  const int sw = m & 7;
#pragma unroll
  for (int ks = 0; ks < K / 32; ++ks) {
    const int ca = ((ks * 4 + quad) ^ sw) << 3;
    bf16x8 a0 = *(const bf16x8*)&As[(m0 + m) * K + ca];
    bf16x8 a1 = *(const bf16x8*)&As[(m0 + 16 + m) * K + ca];
    bf16x8 b0 = *(const bf16x8*)&Bs[(n0 + m) * K + ca];
    bf16x8 b1 = *(const bf16x8*)&Bs[(n0 + 16 + m) * K + ca];
    acc[0][0] = __builtin_amdgcn_mfma_f32_16x16x32_bf16(a0, b0, acc[0][0], 0, 0, 0);
    acc[0][1] = __builtin_amdgcn_mfma_f32_16x16x32_bf16(a0, b1, acc[0][1], 0, 0, 0);
    acc[1][0] = __builtin_amdgcn_mfma_f32_16x16x32_bf16(a1, b0, acc[1][0], 0, 0, 0);
    acc[1][1] = __builtin_amdgcn_mfma_f32_16x16x32_bf16(a1, b1, acc[1][1], 0, 0, 0);
  }

#pragma unroll
  for (int i = 0; i < 2; ++i)
#pragma unroll
    for (int j = 0; j < 2; ++j) {
      const int col = bn + n0 + j * 16 + m;
      const float bv = bias[col];
#pragma unroll
      for (int r = 0; r < 4; ++r) {
        const int row = bm + m0 + i * 16 + quad * 4 + r;
        float v = acc[i][j][r] + bv;
        if (GELU) v = gelu_f(v);
        if (WF) outF[(size_t)row * N + col] = v;
        if (WB) outB[(size_t)row * N + col] = f2bs(v);
      }
    }
}

// out-projection GEMM with FUSED split-merge (deletes k_merge):
// t_ij = (merge(Opart,lpart)) @ Wt_out^T + bias + 2*r, written bf16.
__global__ __launch_bounds__(256) void k_mgemm_out(const short* __restrict__ Opart,
                                                   const float* __restrict__ lpart,
                                                   const short* __restrict__ Bt,
                                                   const float* __restrict__ bias,
                                                   const float* __restrict__ res,
                                                   short* __restrict__ outB) {
  constexpr int K = 256;
  __shared__ alignas(16) short As[64 * K];
  __shared__ alignas(16) short Bs[64 * K];
  const int tid = threadIdx.x;
  const int wave = tid >> 6, lane = tid & 63;
  const int m = lane & 15, quad = lane >> 4;
  const int bm = blockIdx.x * 64, bn = blockIdx.y * 64;
  const int m0 = (wave & 1) * 32, n0 = (wave >> 1) * 32;

  int4 ra[8], rb[8];
#pragma unroll
  for (int i = 0; i < 8; ++i) {
    const int c = tid + (i << 8);
    const int row = c >> 5, kc = c & 31;
    const int R = bm + row, head = kc >> 2;
    float o[8] = {0.f, 0.f, 0.f, 0.f, 0.f, 0.f, 0.f, 0.f};
    float l = 0.f;
#pragma unroll
    for (int s = 0; s < 4; ++s) {
      int4 ov = *(const int4*)(Opart + (size_t)s * 1048576 + (size_t)R * 256 + kc * 8);
      const unsigned short* os = (const unsigned short*)&ov;
#pragma unroll
      for (int j = 0; j < 8; ++j) o[j] += u2f(os[j]);
      l += lpart[(size_t)(s * 8 + head) * 4096 + R];
    }
    const float inv = 1.0f / l;
    unsigned* vu = (unsigned*)&ra[i];
    vu[0] = pk2r(o[0] * inv, o[1] * inv);
    vu[1] = pk2r(o[2] * inv, o[3] * inv);
    vu[2] = pk2r(o[4] * inv, o[5] * inv);
    vu[3] = pk2r(o[6] * inv, o[7] * inv);
    rb[i] = *(const int4*)(Bt + (size_t)(bn + row) * K + kc * 8);
  }
#pragma unroll
  for (int i = 0; i < 8; ++i) {
    const int c = tid + (i << 8);
    const int row = c >> 5, kc = c & 31;
    *(int4*)&As[row * K + ((kc ^ (row & 7)) << 3)] = ra[i];
    *(int4*)&Bs[row * K + ((kc ^ (row & 7)) << 3)] = rb[i];
  }
  __syncthreads();

  f32x4 acc[2][2];
  acc[0][0] = acc[0][1] = acc[1][0] = acc[1][1] = (f32x4){0.f, 0.f, 0.f, 0.f};

  const int sw = m & 7;
#pragma unroll
  for (int ks = 0; ks < K / 32; ++ks) {
    const int ca = ((ks * 4 + quad) ^ sw) << 3;
    bf16x8 a0 = *(const bf16x8*)&As[(m0 + m) * K + ca];
    bf16x8 a1 = *(const bf16x8*)&As[(m0 + 16 + m) * K + ca];
    bf16x8 b0 = *(const bf16x8*)&Bs[(n0 + m) * K + ca];
    bf16x8 b1 = *(const bf16x8*)&Bs[(n0 + 16 + m) * K + ca];
    acc[0][0] = __builtin_amdgcn_mfma_f32_16x16x32_bf16(a0, b0, acc[0][0], 0, 0, 0);
    acc[0][1] = __builtin_amdgcn_mfma_f32_16x16x32_bf16(a0, b1, acc[0][1], 0, 0, 0);
    acc[1][0] = __builtin_amdgcn_mfma_f32_16x16x32_bf16(a1, b0, acc[1][0], 0, 0, 0);
    acc[1][1] = __builtin_amdgcn_mfma_f32_16x16x32_bf16(a1, b1, acc[1][1], 0, 0, 0);
  }

#pragma unroll
  for (int i = 0; i < 2; ++i)
#pragma unroll
    for (int j = 0; j < 2; ++j) {
      const int col = bn + n0 + j * 16 + m;
      const float bv = bias[col];
#pragma unroll
      for (int r = 0; r < 4; ++r) {
        const int row = bm + m0 + i * 16 + quad * 4 + r;
        float v = acc[i][j][r] + bv + 2.0f * res[(size_t)row * 256 + col];
        outB[(size_t)row * 256 + col] = f2bs(v);
      }
    }
}

// qkv variant (K=256, full-K single-barrier staging): writes
// Qh/Kh[head][4096][32] (Q pre-scaled, K linear), Vt[head][32][4096] with
// the in-tile key PERMUTATION baked in:
//   key T -> (T&~63) + ((T>>5)&1)*32 + ((T>>2)&3)*8 + ((T>>4)&1)*4 + (T&3)
// so flash's PV A-fragment needs no LDS round-trip.
__global__ __launch_bounds__(256) void k_mgemm_qkv(const short* __restrict__ A,
                                                   const short* __restrict__ Bt,
                                                   const float* __restrict__ bias,
                                                   short* __restrict__ Qh,
                                                   short* __restrict__ Kh,
                                                   short* __restrict__ Vt) {
  constexpr int K = 256;
  __shared__ alignas(16) short As[64 * K];
  __shared__ alignas(16) short Bs[64 * K];
  const int tid = threadIdx.x;
  const int wave = tid >> 6, lane = tid & 63;
  const int m = lane & 15, quad = lane >> 4;
  const int bm = blockIdx.x * 64, bn = blockIdx.y * 64;
  const int m0 = (wave & 1) * 32, n0 = (wave >> 1) * 32;

  int4 ra[8], rb[8];
#pragma unroll
  for (int i = 0; i < 8; ++i) {
    const int c = tid + (i << 8);
    const int row = c >> 5, kc = c & 31;
    ra[i] = *(const int4*)(A + (size_t)(bm + row) * K + kc * 8);
    rb[i] = *(const int4*)(Bt + (size_t)(bn + row) * K + kc * 8);
  }
#pragma unroll
  for (int i = 0; i < 8; ++i) {
    const int c = tid + (i << 8);
    const int row = c >> 5, kc = c & 31;
    *(int4*)&As[row * K + ((kc ^ (row & 7)) << 3)] = ra[i];
    *(int4*)&Bs[row * K + ((kc ^ (row & 7)) << 3)] = rb[i];
  }
  __syncthreads();

  f32x4 acc[2][2];
  acc[0][0] = acc[0][1] = acc[1][0] = acc[1][1] = (f32x4){0.f, 0.f, 0.f, 0.f};

  const int sw = m & 7;
#pragma unroll
  for (int ks = 0; ks < K / 32; ++ks) {
    const int ca = ((ks * 4 + quad) ^ sw) << 3;
    bf16x8 a0 = *(const bf16x8*)&As[(m0 + m) * K + ca];
    bf16x8 a1 = *(const bf16x8*)&As[(m0 + 16 + m) * K + ca];
    bf16x8 b0 = *(const bf16x8*)&Bs[(n0 + m) * K + ca];
    bf16x8 b1 = *(const bf16x8*)&Bs[(n0 + 16 + m) * K + ca];
    acc[0][0] = __builtin_amdgcn_mfma_f32_16x16x32_bf16(a0, b0, acc[0][0], 0, 0, 0);
    acc[0][1] = __builtin_amdgcn_mfma_f32_16x16x32_bf16(a0, b1, acc[0][1], 0, 0, 0);
    acc[1][0] = __builtin_amdgcn_mfma_f32_16x16x32_bf16(a1, b0, acc[1][0], 0, 0, 0);
    acc[1][1] = __builtin_amdgcn_mfma_f32_16x16x32_bf16(a1, b1, acc[1][1], 0, 0, 0);
  }

#pragma unroll
  for (int i = 0; i < 2; ++i)
#pragma unroll
    for (int j = 0; j < 2; ++j) {
      const int col = bn + n0 + j * 16 + m;
      const float bv = bias[col];
      const int row0 = bm + m0 + i * 16 + quad * 4;
      if (col < 256) {
        const int head = col >> 5, d = col & 31;
#pragma unroll
        for (int r = 0; r < 4; ++r)
          Qh[(size_t)head * 131072 + (row0 + r) * 32 + d] =
              f2bs((acc[i][j][r] + bv) * QSCALE);
      } else if (col < 512) {
        const int c = col - 256, head = c >> 5, d = c & 31;
#pragma unroll
        for (int r = 0; r < 4; ++r)
          Kh[(size_t)head * 131072 + (row0 + r) * 32 + d] = f2bs(acc[i][j][r] + bv);
      } else {
        const int c = col - 512, head = c >> 5, d = c & 31;
        const int p0 = (row0 & ~63) + ((row0 >> 5) & 1) * 32 +
                       ((row0 >> 2) & 3) * 8 + ((row0 >> 4) & 1) * 4;
        ushort4 w;
        w.x = (unsigned short)f2bs(acc[i][j][0] + bv);
        w.y = (unsigned short)f2bs(acc[i][j][1] + bv);
        w.z = (unsigned short)f2bs(acc[i][j][2] + bv);
        w.w = (unsigned short)f2bs(acc[i][j][3] + bv);
        *(ushort4*)(Vt + (size_t)head * 131072 + d * 4096 + p0) = w;
      }
    }
}

// ---------- fused gather-aggregation + LN ----------
__global__ __launch_bounds__(256) void k_rln2(const int* __restrict__ tgt,
                                              const int* __restrict__ cnt,
                                              const int* __restrict__ inv,
                                              const float* __restrict__ h,
                                              const float* __restrict__ g,
                                              const float* __restrict__ b,
                                              float* __restrict__ r,
                                              short* __restrict__ xnb) {
  __shared__ float red1[4], red2[4];
  const int e = blockIdx.x, d = threadIdx.x;
  const int t = tgt[e];
  const int c = cnt[t];
  float S = 0.f;
  for (int j = 0; j < c; ++j)
    S += h[(size_t)inv[t * 8 + j] * HDIM + d];
  float rv = S - (float)c * h[(size_t)e * HDIM + d];
  r[(size_t)e * HDIM + d] = rv;

  float s = rv;
#pragma unroll
  for (int k = 1; k < 64; k <<= 1) s += __shfl_xor(s, k, 64);
  if ((d & 63) == 0) red1[d >> 6] = s;
  __syncthreads();
  float mean = (red1[0] + red1[1] + red1[2] + red1[3]) * (1.0f / HDIM);
  float diff = rv - mean;
  float sq = diff * diff;
#pragma unroll
  for (int k = 1; k < 64; k <<= 1) sq += __shfl_xor(sq, k, 64);
  if ((d & 63) == 0) red2[d >> 6] = sq;
  __syncthreads();
  float var = (red2[0] + red2[1] + red2[2] + red2[3]) * (1.0f / HDIM);
  xnb[(size_t)e * HDIM + d] = f2bs(diff * rsqrtf(var + 1e-5f) * g[d] + b[d]);
}

// h = gelu(LN(u)*g + b); final layer also stores to d_out in probed dtype
__global__ __launch_bounds__(256) void k_ln_gelu(const float* __restrict__ u,
                                                 const float* __restrict__ g,
                                                 const float* __restrict__ b,
                                                 float* __restrict__ hout,
                                                 void* __restrict__ finalout,
                                                 const int* __restrict__ flag) {
  __shared__ float red1[4], red2[4];
  const int e = blockIdx.x, d = threadIdx.x;
  float v = u[(size_t)e * HDIM + d];
  float s = v;
#pragma unroll
  for (int k = 1; k < 64; k <<= 1) s += __shfl_xor(s, k, 64);
  if ((d & 63) == 0) red1[d >> 6] = s;
  __syncthreads();
  float mean = (red1[0] + red1[1] + red1[2] + red1[3]) * (1.0f / HDIM);
  float diff = v - mean;
  float sq = diff * diff;
#pragma unroll
  for (int k = 1; k < 64; k <<= 1) sq += __shfl_xor(sq, k, 64);
  if ((d & 63) == 0) red2[d >> 6] = sq;
  __syncthreads();
  float var = (red2[0] + red2[1] + red2[2] + red2[3]) * (1.0f / HDIM);
  float xh = diff * rsqrtf(var + 1e-5f) * g[d] + b[d];
  float out = gelu_f(xh);
  hout[(size_t)e * HDIM + d] = out;
  if (finalout) {
    if (*flag)
      ((bf16*)finalout)[(size_t)e * HDIM + d] = __float2bfloat16(out);
    else
      ((float*)finalout)[(size_t)e * HDIM + d] = out;
  }
}

// ---------- MFMA flash attention v14: LDS-shared K/V, 128-key tiles ----------
// grid (16, 8, 4); block 256 = 4 waves x 64 q. v13 structure with DOUBLE the
// tile (128 keys): 8 tiles x 2 barriers = 16 barriers (was 32), and each
// compute phase is 2x longer -> staging latency better hidden. Ks[128][40],
// Vs[32][134] (~2-way conflicts, free). P in-register (S^T = mfma(K,Q),
// exp2 + bit-pack, permuted-V PV). Opart bf16.
__global__ __launch_bounds__(256) void k_flash4(const short* __restrict__ Qh,
                                                const short* __restrict__ Kh,
                                                const short* __restrict__ Vt,
                                                short* __restrict__ Opart,
                                                float* __restrict__ lpart) {
  __shared__ alignas(16) short Ks[128 * 40];
  __shared__ alignas(16) short Vs[32 * 134 + 8];
  const int head = blockIdx.y, split = blockIdx.z;
  const int tid = threadIdx.x;
  const int wave = tid >> 6, lane = tid & 63;
  const int m = lane & 15, quad = lane >> 4;
  const int q0 = blockIdx.x * 256 + wave * 64;

  const short* Qb = Qh + (size_t)head * 131072;
  const short* Kb = Kh + (size_t)head * 131072;
  const short* Vb = Vt + (size_t)head * 131072;

  bf16x8 qf[4];
#pragma unroll
  for (int a = 0; a < 4; ++a)
    qf[a] = *(const bf16x8*)(Qb + (q0 + a * 16 + m) * 32 + quad * 8);

  f32x4 O[4][2];
  f32x4 lacc[4];
#pragma unroll
  for (int a = 0; a < 4; ++a) {
    O[a][0] = O[a][1] = (f32x4){0.f, 0.f, 0.f, 0.f};
    lacc[a] = (f32x4){0.f, 0.f, 0.f, 0.f};
  }

  bf16x8 ones;
#pragma unroll
  for (int i = 0; i < 8; ++i) ones[i] = (short)0x3F80;  // bf16 1.0

  const int base = split * 1024;
  // K stage: 128 rows x 32 d = 512 chunks, 2/thread (chunk c: row=c>>2, ko=(c&3)*8)
  // V stage: 32 rows x 128 keys = 512 chunks, 2/thread (row=c>>4, vo=(c&15)*8)
  const int kr = tid >> 2, ko = (tid & 3) * 8;
  const int vr = tid >> 4, vo = (tid & 15) * 8;
  const short* kst = Kb + (size_t)(base + kr) * 32 + ko;   // +2048 for chunk2, +kb*4096
  const short* vst = Vb + (size_t)vr * 4096 + base + vo;   // +65536 for chunk2, +kb*128
  const int kl = kr * 40 + ko;                             // +2560 for chunk2
  const int vl = vr * 134 + vo;                            // +2144 for chunk2

  int4 rk0 = *(const int4*)(kst);
  int4 rk1 = *(const int4*)(kst + 2048);
  int4 rv0 = *(const int4*)(vst);
  int4 rv1 = *(const int4*)(vst + 65536);

#pragma unroll 1
  for (int kb = 0; kb < 8; ++kb) {
    __syncthreads();
    *(int4*)&Ks[kl] = rk0;
    *(int4*)&Ks[kl + 2560] = rk1;
    *(int4*)&Vs[vl] = rv0;
    *(int4*)&Vs[vl + 2144] = rv1;
    __syncthreads();
    if (kb < 7) {
      rk0 = *(const int4*)(kst + (kb + 1) * 4096);
      rk1 = *(const int4*)(kst + (kb + 1) * 4096 + 2048);
      rv0 = *(const int4*)(vst + (kb + 1) * 128);
      rv1 = *(const int4*)(vst + (kb + 1) * 128 + 65536);
    }

    // fragments from LDS
    bf16x8 kc[8];
#pragma unroll
    for (int g = 0; g < 8; ++g)
      kc[g] = *(const bf16x8*)&Ks[(g * 16 + m) * 40 + quad * 8];
    bf16x8 vd0[4], vd1[4];
#pragma unroll
    for (int j = 0; j < 4; ++j) {
      vd0[j] = *(const bf16x8*)&Vs[m * 134 + j * 32 + quad * 8];
      vd1[j] = *(const bf16x8*)&Vs[(m + 16) * 134 + j * 32 + quad * 8];
    }

    const f32x4 z = {0.f, 0.f, 0.f, 0.f};
#pragma unroll
    for (int a = 0; a < 4; ++a) {
      f32x4 S[8];
#pragma unroll
      for (int g = 0; g < 8; ++g)
        S[g] = __builtin_amdgcn_mfma_f32_16x16x32_bf16(kc[g], qf[a], z, 0, 0, 0);

      float e[8][4];
#pragma unroll
      for (int g = 0; g < 8; ++g)
#pragma unroll
        for (int r = 0; r < 4; ++r) e[g][r] = fexp2(S[g][r]);

      union { bf16x8 v; unsigned u[4]; } pf[4];
#pragma unroll
      for (int j = 0; j < 4; ++j) {
        pf[j].u[0] = pk2(e[2 * j][0], e[2 * j][1]);
        pf[j].u[1] = pk2(e[2 * j][2], e[2 * j][3]);
        pf[j].u[2] = pk2(e[2 * j + 1][0], e[2 * j + 1][1]);
        pf[j].u[3] = pk2(e[2 * j + 1][2], e[2 * j + 1][3]);
      }
#pragma unroll
      for (int j = 0; j < 4; ++j) {
        O[a][0] = __builtin_amdgcn_mfma_f32_16x16x32_bf16(pf[j].v, vd0[j], O[a][0], 0, 0, 0);
        O[a][1] = __builtin_amdgcn_mfma_f32_16x16x32_bf16(pf[j].v, vd1[j], O[a][1], 0, 0, 0);
        lacc[a] = __builtin_amdgcn_mfma_f32_16x16x32_bf16(pf[j].v, ones, lacc[a], 0, 0, 0);
      }
    }
  }

#pragma unroll
  for (int a = 0; a < 4; ++a)
#pragma unroll
    for (int r = 0; r < 4; ++r) {
      const int row = q0 + a * 16 + quad * 4 + r;
      short* op = Opart + ((size_t)split * 4096 + row) * 256 + head * 32 + m;
      op[0]  = f2bs(O[a][0][r]);
      op[16] = f2bs(O[a][1][r]);
      if (m == 0) lpart[(size_t)(split * 8 + head) * 4096 + row] = lacc[a][r];
    }
}

// ---------- host launch ----------
extern "C" void kernel_launch(void* const* d_in, const int* in_sizes, int n_in,
                              void* d_out, int out_size, void* d_ws, size_t ws_size,
                              hipStream_t stream) {
  const int* edge = (const int*)d_in[0];
  const int* tgt = edge + NE;

  float* ws = (float*)d_ws;
  float* hbuf   = ws;                        // 1048576
  float* rbuf   = ws + 1048576;              // 1048576
  int* cnt      = (int*)(ws + 2097152);      // 1024
  int* inv      = cnt + 1024;                // 8192
  float* prm    = ws + 2360320;              // 7424 fp32 params
  short* xn_bf  = (short*)(ws + 2367744);    // 1048576 sh
  short* t_bf   = (short*)(ws + 2892032);    // 1048576 sh (out -> up)
  short* Wt     = (short*)(ws + 3416320);    // 1064960 sh
  short* Qh     = (short*)(ws + 3948800);    // 1048576 sh
  short* Kh     = (short*)(ws + 4473088);
  short* Vt     = (short*)(ws + 4997376);
  float* lpart  = ws + 5521664;              // 131072
  float* BIG    = ws + 5652736;              // 4194304 (aliased)
  int* flag     = (int*)(ws + 9847040);

  // BIG aliases (phase-disjoint):
  short* e1_bf   = (short*)(BIG + 131072);   // embed
  short* Opart   = (short*)BIG;              // flash -> fused out GEMM (bf16)
  float* ubuf    = BIG + 524288;             // up -> ln_gelu (Opart dead by then)

  const short* Wt_emb = Wt;
  const short* Wt_h   = Wt + 16384;
  const short* Wt_in  = Wt + 81920;
  const short* Wt_out = Wt + 671744;
  const short* Wt_up  = Wt + 868352;
  const float* b_emb = prm;
  const float* b_h   = prm + 256;
  const float* ln1_g = prm + 512;
  const float* ln1_b = prm + 1280;
  const float* in_b  = prm + 2048;
  const float* out_b = prm + 4352;
  const float* up_b  = prm + 5120;
  const float* ln2_g = prm + 5888;
  const float* ln2_b = prm + 6656;

  k_detect<<<dim3(1), dim3(64), 0, stream>>>((const unsigned*)d_in[2], flag, cnt);
  WPtrs wp = {d_in[2], d_in[4], d_in[8], d_in[10], d_in[12]};
  PPtrs pp = {{d_in[3], d_in[5], d_in[6], d_in[7], d_in[9], d_in[11],
               d_in[13], d_in[14], d_in[15]}};
  k_prep<<<dim3(4205), dim3(256), 0, stream>>>(wp, pp, tgt, Wt, prm, cnt, inv,
                                               flag);

  dim3 blk(256);
  dim3 g256(64, 4);
  dim3 g768(64, 12);
  dim3 gfa(16, 8, 4);

  // embed: e1 = gelu(bond @ W_emb + b_emb)  [bond read raw, dtype-probed]
  k_mgemm<64, true, true, false, true><<<g256, blk, 0, stream>>>(
      (const short*)d_in[1], Wt_emb, b_emb, nullptr, e1_bf, flag, NE, 256);
  // h = e1 @ W_h + b_h
  k_mgemm<256, false, false, true, false><<<g256, blk, 0, stream>>>(
      e1_bf, Wt_h, b_h, hbuf, nullptr, nullptr, NE, 256);

  for (int t = 0; t < 3; ++t) {
    k_rln2<<<dim3(NE), blk, 0, stream>>>(tgt, cnt, inv, hbuf,
                                         ln1_g + t * HDIM, ln1_b + t * HDIM,
                                         rbuf, xn_bf);
    k_mgemm_qkv<<<g768, blk, 0, stream>>>(xn_bf, Wt_in + (size_t)t * 196608,
                                          in_b + t * 768, Qh, Kh, Vt);
    k_flash4<<<gfa, blk, 0, stream>>>(Qh, Kh, Vt, Opart, lpart);
    // t_ij = merge(Opart,lpart) @ Wt_out^T + out_b + 2*r   (merge fused)
    k_mgemm_out<<<g256, blk, 0, stream>>>(Opart, lpart,
                                          Wt_out + (size_t)t * 65536,
                                          out_b + t * 256, rbuf, t_bf);
    // u = t_ij @ Wt_up^T + up_b
    k_mgemm<256, false, false, true, false><<<g256, blk, 0, stream>>>(
        t_bf, Wt_up + (size_t)t * 65536, up_b + t * 256, ubuf, nullptr,
        nullptr, NE, 256);
    k_ln_gelu<<<dim3(NE), blk, 0, stream>>>(ubuf, ln2_g + t * HDIM,
                                            ln2_b + t * HDIM, hbuf,
                                            (t == 2) ? d_out : nullptr, flag);
  }
}